// Round 1
// baseline (253.765 us; speedup 1.0000x reference)
//
#include <hip/hip_runtime.h>
#include <cmath>

typedef _Float16 half8 __attribute__((ext_vector_type(8)));
typedef _Float16 half2v __attribute__((ext_vector_type(2)));
typedef float f32x4 __attribute__((ext_vector_type(4)));

#define B_ 2
#define L_ 2048
#define H_ 8
#define D_ 64
#define S_ 2
#define F_ 5
#define QTILE 64
#define KTILE 64
#define KSTR 72   // LDS stride (halfs) for Ks/VT: 144B rows -> 16B-aligned b128 frag reads
#define PSTR 68   // LDS stride (floats) for P: 272B rows -> 16B-aligned float4 reads

// One block: (b, h, 64 q-rows). 4 waves, each owns 16 q-rows.
// Flash loop over 32 K-tiles of 64 keys. f16 MFMA 16x16x32 for QK^T and PV.
__global__ __launch_bounds__(256, 2)
void tisa_attn_kernel(const float* __restrict__ qs, const float* __restrict__ ks,
                      const float* __restrict__ vs, const float* __restrict__ qs_s,
                      const float* __restrict__ ks_s, const float* __restrict__ ap,
                      const float* __restrict__ bp, const float* __restrict__ cp,
                      float* __restrict__ out) {
  __shared__ _Float16 Ks[KTILE * KSTR];   // K tile, natural [key][d] (f16)
  __shared__ _Float16 VT[D_ * KSTR];      // V tile, transposed [d][key] (f16)
  __shared__ float Pl[4][16 * PSTR];      // per-wave P tile [qrow][key] (f32)
  __shared__ float kss[KTILE * 2];        // ks_s coords for tile

  const int t    = threadIdx.x;
  const int lane = t & 63;
  const int wq   = t >> 6;      // wave id 0..3
  const int quad = lane >> 4;   // 0..3
  const int l16  = lane & 15;

  const int blk = blockIdx.x;
  const int qt  = blk & 31;     // 32 q-tiles
  const int bh  = blk >> 5;
  const int h   = bh & 7;
  const int b   = bh >> 3;
  const int q0  = qt * QTILE;

  // Per-head gaussian params (block-uniform -> scalarized by compiler)
  float af[F_], nb[F_], cf[F_];
#pragma unroll
  for (int f = 0; f < F_; ++f) {
    af[f] = ap[h * F_ + f];
    nb[f] = -fabsf(bp[h * F_ + f]);
    cf[f] = cp[h * F_ + f];
  }

  // q coords for this lane's 4 C-layout rows (row = wq*16 + quad*4 + r)
  float qx[4], qy[4];
#pragma unroll
  for (int r = 0; r < 4; ++r) {
    int qrow = q0 + wq * 16 + quad * 4 + r;
    qx[r] = qs_s[(b * L_ + qrow) * S_ + 0];
    qy[r] = qs_s[(b * L_ + qrow) * S_ + 1];
  }

  // ---- stage Q (pre-scaled by 1/sqrt(D)=0.125) into Ks buffer, grab A-frags ----
  {
    const int row = t >> 2;            // 0..63
    const int dc  = (t & 3) * 16;      // 0,16,32,48
    const float* src = qs + (((size_t)(b * L_ + q0 + row)) * H_ + h) * D_ + dc;
    const f32x4* s4 = (const f32x4*)src;
    f32x4 v0 = s4[0], v1 = s4[1], v2 = s4[2], v3 = s4[3];
    half8 w0, w1;
#pragma unroll
    for (int u = 0; u < 4; ++u) {
      w0[u]     = (_Float16)(v0[u] * 0.125f);
      w0[u + 4] = (_Float16)(v1[u] * 0.125f);
      w1[u]     = (_Float16)(v2[u] * 0.125f);
      w1[u + 4] = (_Float16)(v3[u] * 0.125f);
    }
    *(half8*)&Ks[row * KSTR + dc]     = w0;
    *(half8*)&Ks[row * KSTR + dc + 8] = w1;
  }
  __syncthreads();
  // A-frag: A[m=lane&15][k=quad*8+j]  (verified layout, m120)
  half8 qA[2];
#pragma unroll
  for (int kb = 0; kb < 2; ++kb)
    qA[kb] = *(const half8*)&Ks[(wq * 16 + l16) * KSTR + kb * 32 + quad * 8];

  // O accumulators: C-layout, oc[df][r] = O[row=quad*4+r][d=df*16+l16]
  f32x4 oc[4];
#pragma unroll
  for (int df = 0; df < 4; ++df) oc[df] = (f32x4){0.f, 0.f, 0.f, 0.f};
  float m_r[4], l_r[4];
#pragma unroll
  for (int r = 0; r < 4; ++r) { m_r[r] = -INFINITY; l_r[r] = 0.f; }

  for (int kt = 0; kt < L_ / KTILE; ++kt) {
    const int k0 = kt * KTILE;
    __syncthreads();  // previous tile's Ks/VT/P reads complete (also guards qA reads, iter 0)

    // ---- stage K tile (natural layout, f16) ----
    {
      const int row = t >> 2;
      const int dc  = (t & 3) * 16;
      const float* src = ks + (((size_t)(b * L_ + k0 + row)) * H_ + h) * D_ + dc;
      const f32x4* s4 = (const f32x4*)src;
      f32x4 v0 = s4[0], v1 = s4[1], v2 = s4[2], v3 = s4[3];
      half8 w0, w1;
#pragma unroll
      for (int u = 0; u < 4; ++u) {
        w0[u]     = (_Float16)v0[u];
        w0[u + 4] = (_Float16)v1[u];
        w1[u]     = (_Float16)v2[u];
        w1[u + 4] = (_Float16)v3[u];
      }
      *(half8*)&Ks[row * KSTR + dc]     = w0;
      *(half8*)&Ks[row * KSTR + dc + 8] = w1;
    }
    // ---- stage V tile transposed: VT[d][k], f16 ----
    {
      const int kk = (t & 31) * 2;       // key pair
      const int dg = (t >> 5) * 8;       // 8 d-values
      const float* s0 = vs + (((size_t)(b * L_ + k0 + kk)) * H_ + h) * D_ + dg;
      const float* s1 = s0 + H_ * D_;    // next key row
      f32x4 a0 = ((const f32x4*)s0)[0], a1 = ((const f32x4*)s0)[1];
      f32x4 b0 = ((const f32x4*)s1)[0], b1 = ((const f32x4*)s1)[1];
#pragma unroll
      for (int u = 0; u < 4; ++u) {
        half2v p0 = { (_Float16)a0[u], (_Float16)b0[u] };
        *(half2v*)&VT[(dg + u) * KSTR + kk] = p0;
        half2v p1 = { (_Float16)a1[u], (_Float16)b1[u] };
        *(half2v*)&VT[(dg + 4 + u) * KSTR + kk] = p1;
      }
    }
    if (t < 128) kss[t] = ks_s[((size_t)(b * L_) + k0 + (t >> 1)) * S_ + (t & 1)];
    __syncthreads();

    // ---- QK^T: S[16 q][64 k], 4 col-frags x 2 K-chunks ----
    f32x4 acc[4];
#pragma unroll
    for (int nf = 0; nf < 4; ++nf) {
      f32x4 a = (f32x4){0.f, 0.f, 0.f, 0.f};
#pragma unroll
      for (int kb = 0; kb < 2; ++kb) {
        // B^T-style read: K[key=nf*16+l16][d=kb*32+quad*8+j]
        half8 kf = *(const half8*)&Ks[(nf * 16 + l16) * KSTR + kb * 32 + quad * 8];
        a = __builtin_amdgcn_mfma_f32_16x16x32_f16(qA[kb], kf, a, 0, 0, 0);
      }
      acc[nf] = a;
    }

    // ---- bias: sum_f a*exp(-|b|*(dist-c)^2), dist from 2-D scan coords ----
#pragma unroll
    for (int nf = 0; nf < 4; ++nf) {
      float kx = kss[(nf * 16 + l16) * 2 + 0];
      float ky = kss[(nf * 16 + l16) * 2 + 1];
#pragma unroll
      for (int r = 0; r < 4; ++r) {
        float dx = qx[r] - kx, dy = qy[r] - ky;
        float dist = sqrtf(dx * dx + dy * dy);
        float bias = 0.f;
#pragma unroll
        for (int f = 0; f < F_; ++f) {
          float dd = dist - cf[f];
          bias += af[f] * __expf(nb[f] * (dd * dd));
        }
        acc[nf][r] += bias;
      }
    }

    // ---- online softmax (per C-layout row; reduce across l16 within quad) ----
    float alpha[4];
#pragma unroll
    for (int r = 0; r < 4; ++r) {
      float mm = fmaxf(fmaxf(acc[0][r], acc[1][r]), fmaxf(acc[2][r], acc[3][r]));
      mm = fmaxf(mm, __shfl_xor(mm, 1));
      mm = fmaxf(mm, __shfl_xor(mm, 2));
      mm = fmaxf(mm, __shfl_xor(mm, 4));
      mm = fmaxf(mm, __shfl_xor(mm, 8));
      float mnew = fmaxf(m_r[r], mm);
      alpha[r] = __expf(m_r[r] - mnew);   // exp(-inf)=0 on first tile
      m_r[r] = mnew;
      float s = 0.f;
#pragma unroll
      for (int nf = 0; nf < 4; ++nf) {
        float p = __expf(acc[nf][r] - mnew);
        acc[nf][r] = p;
        s += p;
      }
      s += __shfl_xor(s, 1);
      s += __shfl_xor(s, 2);
      s += __shfl_xor(s, 4);
      s += __shfl_xor(s, 8);
      l_r[r] = l_r[r] * alpha[r] + s;
    }
#pragma unroll
    for (int df = 0; df < 4; ++df)
#pragma unroll
      for (int r = 0; r < 4; ++r) oc[df][r] *= alpha[r];

    // ---- P: C-layout regs -> per-wave LDS [qrow][key] ----
#pragma unroll
    for (int nf = 0; nf < 4; ++nf)
#pragma unroll
      for (int r = 0; r < 4; ++r)
        Pl[wq][(quad * 4 + r) * PSTR + nf * 16 + l16] = acc[nf][r];
    __syncthreads();  // P visible (per-wave region; barrier also forces LDS ordering)

    // ---- PV: O += P * V ----
#pragma unroll
    for (int kb = 0; kb < 2; ++kb) {
      const float* pr = &Pl[wq][l16 * PSTR + kb * 32 + quad * 8];
      f32x4 p0 = *(const f32x4*)pr;
      f32x4 p1 = *(const f32x4*)(pr + 4);
      half8 pa;
#pragma unroll
      for (int u = 0; u < 4; ++u) { pa[u] = (_Float16)p0[u]; pa[u + 4] = (_Float16)p1[u]; }
#pragma unroll
      for (int df = 0; df < 4; ++df) {
        // B-frag: V[key=kb*32+quad*8+j][d=df*16+l16] == VT[d][key]
        half8 vf = *(const half8*)&VT[(df * 16 + l16) * KSTR + kb * 32 + quad * 8];
        oc[df] = __builtin_amdgcn_mfma_f32_16x16x32_f16(pa, vf, oc[df], 0, 0, 0);
      }
    }
  }

  // ---- epilogue: divide by l, store ----
  float inv_l[4];
#pragma unroll
  for (int r = 0; r < 4; ++r) inv_l[r] = 1.f / l_r[r];
#pragma unroll
  for (int df = 0; df < 4; ++df)
#pragma unroll
    for (int r = 0; r < 4; ++r) {
      int qrow = q0 + wq * 16 + quad * 4 + r;
      out[(((size_t)(b * L_ + qrow)) * H_ + h) * D_ + df * 16 + l16] = oc[df][r] * inv_l[r];
    }
}

extern "C" void kernel_launch(void* const* d_in, const int* in_sizes, int n_in,
                              void* d_out, int out_size, void* d_ws, size_t ws_size,
                              hipStream_t stream) {
  const float* qs   = (const float*)d_in[0];
  const float* ks   = (const float*)d_in[1];
  const float* vs   = (const float*)d_in[2];
  const float* qs_s = (const float*)d_in[3];
  const float* ks_s = (const float*)d_in[4];
  const float* ap   = (const float*)d_in[5];
  const float* bp   = (const float*)d_in[6];
  const float* cp   = (const float*)d_in[7];
  float* out = (float*)d_out;

  dim3 grid(B_ * H_ * (L_ / QTILE));  // 512 blocks
  dim3 block(256);
  tisa_attn_kernel<<<grid, block, 0, stream>>>(qs, ks, vs, qs_s, ks_s, ap, bp, cp, out);
}

// Round 2
// 191.789 us; speedup vs baseline: 1.3231x; 1.3231x over previous
//
#include <hip/hip_runtime.h>
#include <cmath>

typedef _Float16 half8 __attribute__((ext_vector_type(8)));
typedef _Float16 half2v __attribute__((ext_vector_type(2)));
typedef float f32x4 __attribute__((ext_vector_type(4)));

#define B_ 2
#define L_ 2048
#define H_ 8
#define D_ 64
#define S_ 2
#define F_ 5
#define QTILE 64
#define KTILE 64
#define KSTR 72   // LDS stride (halfs): 144B rows -> 16B-aligned b128 frag reads, 2-way banks (free)
#define PH   72   // P tile stride (halfs)
#define LUTN 1024
#define LSCALE 724.07733f   // LUTN / sqrt(2)

// One block: (b, h, 64 q-rows). 4 waves, each owns 16 q-rows.
// Flash loop over 32 K-tiles of 64 keys. f16 MFMA 16x16x32 for QK^T and PV.
// Bias via per-head LDS LUT over dist; fixed-shift softmax (no running max):
//   p = exp(qk/8 + bias - 8)  -- overflow-safe (scores bounded ~<11), shift cancels in O/l.
__global__ __launch_bounds__(256, 2)
void tisa_attn_kernel(const float* __restrict__ qs, const float* __restrict__ ks,
                      const float* __restrict__ vs, const float* __restrict__ qs_s,
                      const float* __restrict__ ks_s, const float* __restrict__ ap,
                      const float* __restrict__ bp, const float* __restrict__ cp,
                      float* __restrict__ out) {
  __shared__ _Float16 Ks[KTILE * KSTR];   // K tile, natural [key][d] (f16)
  __shared__ _Float16 VT[D_ * KSTR];      // V tile, transposed [d][key] (f16)
  __shared__ _Float16 Pf[4][16 * PH];     // per-wave P tile [qrow][key] (f16)
  __shared__ float kss[KTILE * 2];        // ks_s coords for tile
  __shared__ float LUT[LUTN + 2];         // bias(d) - 8, d = i/LSCALE

  const int t    = threadIdx.x;
  const int lane = t & 63;
  const int wq   = t >> 6;      // wave id 0..3
  const int quad = lane >> 4;   // 0..3
  const int l16  = lane & 15;

  const int blk = blockIdx.x;
  const int qt  = blk & 31;     // 32 q-tiles
  const int bh  = blk >> 5;
  const int h   = bh & 7;
  const int b   = bh >> 3;
  const int q0  = qt * QTILE;

  // Per-head gaussian params (block-uniform -> scalarized by compiler)
  float af[F_], nb[F_], cf[F_];
#pragma unroll
  for (int f = 0; f < F_; ++f) {
    af[f] = ap[h * F_ + f];
    nb[f] = -fabsf(bp[h * F_ + f]);
    cf[f] = cp[h * F_ + f];
  }

  // ---- build bias LUT (once per block): LUT[i] = bias(i/LSCALE) - 8 ----
  for (int i = t; i < LUTN + 2; i += 256) {
    float d = (float)i * (1.0f / LSCALE);
    float s = 0.f;
#pragma unroll
    for (int f = 0; f < F_; ++f) {
      float dd = d - cf[f];
      s += af[f] * __expf(nb[f] * (dd * dd));
    }
    LUT[i] = s - 8.0f;
  }

  // q coords for this lane's 4 C-layout rows (row = wq*16 + quad*4 + r)
  float qx[4], qy[4];
#pragma unroll
  for (int r = 0; r < 4; ++r) {
    int qrow = q0 + wq * 16 + quad * 4 + r;
    qx[r] = qs_s[(b * L_ + qrow) * S_ + 0];
    qy[r] = qs_s[(b * L_ + qrow) * S_ + 1];
  }

  // ---- stage Q (pre-scaled by 1/sqrt(D)=0.125) into Ks buffer, grab A-frags ----
  {
    const int row = t >> 2;            // 0..63
    const int dc  = (t & 3) * 16;      // 0,16,32,48
    const float* src = qs + (((size_t)(b * L_ + q0 + row)) * H_ + h) * D_ + dc;
    const f32x4* s4 = (const f32x4*)src;
    f32x4 v0 = s4[0], v1 = s4[1], v2 = s4[2], v3 = s4[3];
    half8 w0, w1;
#pragma unroll
    for (int u = 0; u < 4; ++u) {
      w0[u]     = (_Float16)(v0[u] * 0.125f);
      w0[u + 4] = (_Float16)(v1[u] * 0.125f);
      w1[u]     = (_Float16)(v2[u] * 0.125f);
      w1[u + 4] = (_Float16)(v3[u] * 0.125f);
    }
    *(half8*)&Ks[row * KSTR + dc]     = w0;
    *(half8*)&Ks[row * KSTR + dc + 8] = w1;
  }
  __syncthreads();  // Q staged + LUT built
  // A-frag: A[m=lane&15][k=quad*8+j]  (verified layout, m120)
  half8 qA[2];
#pragma unroll
  for (int kb = 0; kb < 2; ++kb)
    qA[kb] = *(const half8*)&Ks[(wq * 16 + l16) * KSTR + kb * 32 + quad * 8];

  // O accumulators: C-layout, oc[df][r] = O[row=quad*4+r][d=df*16+l16]
  f32x4 oc[4];
#pragma unroll
  for (int df = 0; df < 4; ++df) oc[df] = (f32x4){0.f, 0.f, 0.f, 0.f};
  float l_r[4];
#pragma unroll
  for (int r = 0; r < 4; ++r) l_r[r] = 0.f;

  for (int kt = 0; kt < L_ / KTILE; ++kt) {
    const int k0 = kt * KTILE;
    __syncthreads();  // previous tile's Ks/VT reads complete (also guards qA reads, iter 0)

    // ---- stage K tile (natural layout, f16) ----
    {
      const int row = t >> 2;
      const int dc  = (t & 3) * 16;
      const float* src = ks + (((size_t)(b * L_ + k0 + row)) * H_ + h) * D_ + dc;
      const f32x4* s4 = (const f32x4*)src;
      f32x4 v0 = s4[0], v1 = s4[1], v2 = s4[2], v3 = s4[3];
      half8 w0, w1;
#pragma unroll
      for (int u = 0; u < 4; ++u) {
        w0[u]     = (_Float16)v0[u];
        w0[u + 4] = (_Float16)v1[u];
        w1[u]     = (_Float16)v2[u];
        w1[u + 4] = (_Float16)v3[u];
      }
      *(half8*)&Ks[row * KSTR + dc]     = w0;
      *(half8*)&Ks[row * KSTR + dc + 8] = w1;
    }
    // ---- stage V tile transposed: VT[d][k], f16 ----
    {
      const int kk = (t & 31) * 2;       // key pair
      const int dg = (t >> 5) * 8;       // 8 d-values
      const float* s0 = vs + (((size_t)(b * L_ + k0 + kk)) * H_ + h) * D_ + dg;
      const float* s1 = s0 + H_ * D_;    // next key row
      f32x4 a0 = ((const f32x4*)s0)[0], a1 = ((const f32x4*)s0)[1];
      f32x4 b0 = ((const f32x4*)s1)[0], b1 = ((const f32x4*)s1)[1];
#pragma unroll
      for (int u = 0; u < 4; ++u) {
        half2v p0 = { (_Float16)a0[u], (_Float16)b0[u] };
        *(half2v*)&VT[(dg + u) * KSTR + kk] = p0;
        half2v p1 = { (_Float16)a1[u], (_Float16)b1[u] };
        *(half2v*)&VT[(dg + 4 + u) * KSTR + kk] = p1;
      }
    }
    if (t < 128) kss[t] = ks_s[((size_t)(b * L_) + k0 + (t >> 1)) * S_ + (t & 1)];
    __syncthreads();

    // ---- QK^T: S[16 q][64 k], 4 col-frags x 2 K-chunks ----
    f32x4 acc[4];
#pragma unroll
    for (int nf = 0; nf < 4; ++nf) {
      f32x4 a = (f32x4){0.f, 0.f, 0.f, 0.f};
#pragma unroll
      for (int kb = 0; kb < 2; ++kb) {
        // B^T-style read: K[key=nf*16+l16][d=kb*32+quad*8+j]
        half8 kf = *(const half8*)&Ks[(nf * 16 + l16) * KSTR + kb * 32 + quad * 8];
        a = __builtin_amdgcn_mfma_f32_16x16x32_f16(qA[kb], kf, a, 0, 0, 0);
      }
      acc[nf] = a;
    }

    // ---- bias via LUT + fixed-shift softmax exp, accumulate row sums ----
#pragma unroll
    for (int nf = 0; nf < 4; ++nf) {
      float kx = kss[(nf * 16 + l16) * 2 + 0];
      float ky = kss[(nf * 16 + l16) * 2 + 1];
#pragma unroll
      for (int r = 0; r < 4; ++r) {
        float dx = qx[r] - kx, dy = qy[r] - ky;
        float dist = sqrtf(fmaf(dx, dx, dy * dy));
        float tt = dist * LSCALE;          // < 1024 since dist < sqrt(2)
        int ii = (int)tt;
        float fr = tt - (float)ii;
        float lo = LUT[ii], hi = LUT[ii + 1];
        float p = __expf(acc[nf][r] + fmaf(fr, hi - lo, lo));
        acc[nf][r] = p;
      }
    }
#pragma unroll
    for (int r = 0; r < 4; ++r)
      l_r[r] += (acc[0][r] + acc[1][r]) + (acc[2][r] + acc[3][r]);

    // ---- P (f16): C-layout regs -> per-wave LDS [qrow][key]; same-wave, no barrier ----
#pragma unroll
    for (int nf = 0; nf < 4; ++nf)
#pragma unroll
      for (int r = 0; r < 4; ++r)
        Pf[wq][(quad * 4 + r) * PH + nf * 16 + l16] = (_Float16)acc[nf][r];

    // ---- PV: O += P * V ----
#pragma unroll
    for (int kb = 0; kb < 2; ++kb) {
      half8 pa = *(const half8*)&Pf[wq][l16 * PH + kb * 32 + quad * 8];
#pragma unroll
      for (int df = 0; df < 4; ++df) {
        // B-frag: V[key=kb*32+quad*8+j][d=df*16+l16] == VT[d][key]
        half8 vf = *(const half8*)&VT[(df * 16 + l16) * KSTR + kb * 32 + quad * 8];
        oc[df] = __builtin_amdgcn_mfma_f32_16x16x32_f16(pa, vf, oc[df], 0, 0, 0);
      }
    }
  }

  // ---- epilogue: reduce row sums across l16, divide, store ----
  float inv_l[4];
#pragma unroll
  for (int r = 0; r < 4; ++r) {
    float s = l_r[r];
    s += __shfl_xor(s, 1);
    s += __shfl_xor(s, 2);
    s += __shfl_xor(s, 4);
    s += __shfl_xor(s, 8);
    inv_l[r] = 1.f / s;
  }
#pragma unroll
  for (int df = 0; df < 4; ++df)
#pragma unroll
    for (int r = 0; r < 4; ++r) {
      int qrow = q0 + wq * 16 + quad * 4 + r;
      out[(((size_t)(b * L_ + qrow)) * H_ + h) * D_ + df * 16 + l16] = oc[df][r] * inv_l[r];
    }
}

extern "C" void kernel_launch(void* const* d_in, const int* in_sizes, int n_in,
                              void* d_out, int out_size, void* d_ws, size_t ws_size,
                              hipStream_t stream) {
  const float* qs   = (const float*)d_in[0];
  const float* ks   = (const float*)d_in[1];
  const float* vs   = (const float*)d_in[2];
  const float* qs_s = (const float*)d_in[3];
  const float* ks_s = (const float*)d_in[4];
  const float* ap   = (const float*)d_in[5];
  const float* bp   = (const float*)d_in[6];
  const float* cp   = (const float*)d_in[7];
  float* out = (float*)d_out;

  dim3 grid(B_ * H_ * (L_ / QTILE));  // 512 blocks
  dim3 block(256);
  tisa_attn_kernel<<<grid, block, 0, stream>>>(qs, ks, vs, qs_s, ks_s, ap, bp, cp, out);
}

// Round 3
// 169.766 us; speedup vs baseline: 1.4948x; 1.1297x over previous
//
#include <hip/hip_runtime.h>
#include <cmath>

typedef _Float16 half8 __attribute__((ext_vector_type(8)));
typedef _Float16 half2v __attribute__((ext_vector_type(2)));
typedef float f32x4 __attribute__((ext_vector_type(4)));
typedef float f32x2 __attribute__((ext_vector_type(2)));

#define B_ 2
#define L_ 2048
#define H_ 8
#define D_ 64
#define S_ 2
#define F_ 5
#define QTILE 64
#define KTILE 64
#define KSTR 72   // LDS stride (halfs): 144B rows -> 16B-aligned b128 frag reads
#define PH   72   // P tile stride (halfs)
#define LUTN 512
#define LSCALE 362.03867f   // LUTN / sqrt(2)

// 512 threads = 8 waves = 4 q-slices x 2 K-halves. Each wave: 16 qrows, 16 K-tiles.
// Fixed-shift softmax (p = exp(qk/8 + bias - 8), no running max) => K-partials
// combine by pure addition; the two K-halves merge through LDS at the end.
// Bias via per-head float2 LDS LUT over dist (one ds_read_b64 per score).
__global__ __launch_bounds__(512, 4)
void tisa_attn_kernel(const float* __restrict__ qs, const float* __restrict__ ks,
                      const float* __restrict__ vs, const float* __restrict__ qs_s,
                      const float* __restrict__ ks_s, const float* __restrict__ ap,
                      const float* __restrict__ bp, const float* __restrict__ cp,
                      float* __restrict__ out) {
  __shared__ _Float16 Ks[2][KTILE * KSTR];  // per-group K tile [key][d] (f16); Ks[0] doubles as Q stage
  __shared__ _Float16 VT[2][D_ * KSTR];     // per-group V tile transposed [d][key] (f16)
  __shared__ _Float16 Pf[8][16 * PH];       // per-wave P tile [qrow][key] (f16)
  __shared__ float kss2[2][KTILE * 2];      // per-group ks_s coords
  __shared__ f32x2 LUT2[LUTN + 1];          // {bias(d_i)-8, bias(d_{i+1})-8}
  __shared__ float comb[4][16][64];         // group-1 partial O for combine
  __shared__ float combl[4][16];            // group-1 partial row sums

  const int t    = threadIdx.x;
  const int lane = t & 63;
  const int w    = t >> 6;      // wave id 0..7
  const int g    = w >> 2;      // K-half 0/1
  const int qw   = w & 3;       // q-slice 0..3
  const int t2   = t & 255;     // index within K-half group
  const int quad = lane >> 4;   // 0..3
  const int l16  = lane & 15;

  const int blk = blockIdx.x;
  const int qt  = blk & 31;     // 32 q-tiles
  const int bh  = blk >> 5;
  const int h   = bh & 7;
  const int b   = bh >> 3;
  const int q0  = qt * QTILE;

  // Per-head gaussian params (block-uniform -> scalarized)
  float af[F_], nb[F_], cf[F_];
#pragma unroll
  for (int f = 0; f < F_; ++f) {
    af[f] = ap[h * F_ + f];
    nb[f] = -fabsf(bp[h * F_ + f]);
    cf[f] = cp[h * F_ + f];
  }

  // ---- build bias LUT (once per block): LUT2[i] = {bias(i/S)-8, bias((i+1)/S)-8} ----
  for (int i = t; i <= LUTN; i += 512) {
    float d0 = (float)i * (1.0f / LSCALE);
    float d1 = (float)(i + 1) * (1.0f / LSCALE);
    float s0 = 0.f, s1 = 0.f;
#pragma unroll
    for (int f = 0; f < F_; ++f) {
      float e0 = d0 - cf[f], e1 = d1 - cf[f];
      s0 += af[f] * __expf(nb[f] * (e0 * e0));
      s1 += af[f] * __expf(nb[f] * (e1 * e1));
    }
    LUT2[i] = (f32x2){s0 - 8.0f, s1 - 8.0f};
  }

  // q coords for this lane's 4 C-layout rows (row = qw*16 + quad*4 + r)
  float qx[4], qy[4];
#pragma unroll
  for (int r = 0; r < 4; ++r) {
    int qrow = q0 + qw * 16 + quad * 4 + r;
    qx[r] = qs_s[(b * L_ + qrow) * S_ + 0];
    qy[r] = qs_s[(b * L_ + qrow) * S_ + 1];
  }

  // ---- stage Q (pre-scaled by 1/8) into Ks[0], grab A-frags ----
  if (t < 256) {
    const int row = t >> 2;            // 0..63
    const int dc  = (t & 3) * 16;      // 0,16,32,48
    const float* src = qs + (((size_t)(b * L_ + q0 + row)) * H_ + h) * D_ + dc;
    const f32x4* s4 = (const f32x4*)src;
    f32x4 v0 = s4[0], v1 = s4[1], v2 = s4[2], v3 = s4[3];
    half8 w0, w1;
#pragma unroll
    for (int u = 0; u < 4; ++u) {
      w0[u]     = (_Float16)(v0[u] * 0.125f);
      w0[u + 4] = (_Float16)(v1[u] * 0.125f);
      w1[u]     = (_Float16)(v2[u] * 0.125f);
      w1[u + 4] = (_Float16)(v3[u] * 0.125f);
    }
    *(half8*)&Ks[0][row * KSTR + dc]     = w0;
    *(half8*)&Ks[0][row * KSTR + dc + 8] = w1;
  }
  __syncthreads();  // Q staged + LUT built
  // A-frag: A[m=lane&15][k=quad*8+j]
  half8 qA[2];
#pragma unroll
  for (int kb = 0; kb < 2; ++kb)
    qA[kb] = *(const half8*)&Ks[0][(qw * 16 + l16) * KSTR + kb * 32 + quad * 8];

  // O accumulators: C-layout, oc[df][r] = O[row=quad*4+r][d=df*16+l16]
  f32x4 oc[4];
#pragma unroll
  for (int df = 0; df < 4; ++df) oc[df] = (f32x4){0.f, 0.f, 0.f, 0.f};
  float l_r[4];
#pragma unroll
  for (int r = 0; r < 4; ++r) l_r[r] = 0.f;

  for (int it = 0; it < 16; ++it) {
    const int k0 = (g * 16 + it) * KTILE;
    __syncthreads();  // previous tile's Ks/VT reads complete (also guards qA reads, it 0)

    // ---- stage K tile (group's 256 threads) ----
    {
      const int row = t2 >> 2;
      const int dc  = (t2 & 3) * 16;
      const float* src = ks + (((size_t)(b * L_ + k0 + row)) * H_ + h) * D_ + dc;
      const f32x4* s4 = (const f32x4*)src;
      f32x4 v0 = s4[0], v1 = s4[1], v2 = s4[2], v3 = s4[3];
      half8 w0, w1;
#pragma unroll
      for (int u = 0; u < 4; ++u) {
        w0[u]     = (_Float16)v0[u];
        w0[u + 4] = (_Float16)v1[u];
        w1[u]     = (_Float16)v2[u];
        w1[u + 4] = (_Float16)v3[u];
      }
      *(half8*)&Ks[g][row * KSTR + dc]     = w0;
      *(half8*)&Ks[g][row * KSTR + dc + 8] = w1;
    }
    // ---- stage V tile transposed: VT[d][k] ----
    {
      const int kk = (t2 & 31) * 2;       // key pair
      const int dg = (t2 >> 5) * 8;       // 8 d-values
      const float* s0 = vs + (((size_t)(b * L_ + k0 + kk)) * H_ + h) * D_ + dg;
      const float* s1 = s0 + H_ * D_;     // next key row
      f32x4 a0 = ((const f32x4*)s0)[0], a1 = ((const f32x4*)s0)[1];
      f32x4 b0 = ((const f32x4*)s1)[0], b1 = ((const f32x4*)s1)[1];
#pragma unroll
      for (int u = 0; u < 4; ++u) {
        half2v p0 = { (_Float16)a0[u], (_Float16)b0[u] };
        *(half2v*)&VT[g][(dg + u) * KSTR + kk] = p0;
        half2v p1 = { (_Float16)a1[u], (_Float16)b1[u] };
        *(half2v*)&VT[g][(dg + 4 + u) * KSTR + kk] = p1;
      }
    }
    if (t2 < 128) kss2[g][t2] = ks_s[((size_t)(b * L_) + k0 + (t2 >> 1)) * S_ + (t2 & 1)];
    __syncthreads();

    // ---- QK^T ----
    f32x4 acc[4];
#pragma unroll
    for (int nf = 0; nf < 4; ++nf) {
      f32x4 a = (f32x4){0.f, 0.f, 0.f, 0.f};
#pragma unroll
      for (int kb = 0; kb < 2; ++kb) {
        half8 kf = *(const half8*)&Ks[g][(nf * 16 + l16) * KSTR + kb * 32 + quad * 8];
        a = __builtin_amdgcn_mfma_f32_16x16x32_f16(qA[kb], kf, a, 0, 0, 0);
      }
      acc[nf] = a;
    }

    // ---- bias via LUT (b64 gather) + fixed-shift softmax exp ----
#pragma unroll
    for (int nf = 0; nf < 4; ++nf) {
      float kx = kss2[g][(nf * 16 + l16) * 2 + 0];
      float ky = kss2[g][(nf * 16 + l16) * 2 + 1];
#pragma unroll
      for (int r = 0; r < 4; ++r) {
        float dx = qx[r] - kx, dy = qy[r] - ky;
        float dist = sqrtf(fmaf(dx, dx, dy * dy));
        float tt = dist * LSCALE;          // < 512 since dist < sqrt(2)
        int ii = (int)tt;
        float fr = tt - (float)ii;
        f32x2 lh = LUT2[ii];
        float p = __expf(acc[nf][r] + fmaf(fr, lh.y - lh.x, lh.x));
        acc[nf][r] = p;
      }
    }
#pragma unroll
    for (int r = 0; r < 4; ++r)
      l_r[r] += (acc[0][r] + acc[1][r]) + (acc[2][r] + acc[3][r]);

    // ---- P (f16) -> per-wave LDS; same-wave, no barrier needed ----
#pragma unroll
    for (int nf = 0; nf < 4; ++nf)
#pragma unroll
      for (int r = 0; r < 4; ++r)
        Pf[w][(quad * 4 + r) * PH + nf * 16 + l16] = (_Float16)acc[nf][r];

    // ---- PV: O += P * V ----
#pragma unroll
    for (int kb = 0; kb < 2; ++kb) {
      half8 pa = *(const half8*)&Pf[w][l16 * PH + kb * 32 + quad * 8];
#pragma unroll
      for (int df = 0; df < 4; ++df) {
        half8 vf = *(const half8*)&VT[g][(df * 16 + l16) * KSTR + kb * 32 + quad * 8];
        oc[df] = __builtin_amdgcn_mfma_f32_16x16x32_f16(pa, vf, oc[df], 0, 0, 0);
      }
    }
  }

  // ---- combine the two K-halves through LDS ----
  __syncthreads();  // all loop LDS traffic done
  // per-row partial sums: reduce across l16 within quad
  float lred[4];
#pragma unroll
  for (int r = 0; r < 4; ++r) {
    float s = l_r[r];
    s += __shfl_xor(s, 1);
    s += __shfl_xor(s, 2);
    s += __shfl_xor(s, 4);
    s += __shfl_xor(s, 8);
    lred[r] = s;
  }
  if (g == 1) {
#pragma unroll
    for (int df = 0; df < 4; ++df)
#pragma unroll
      for (int r = 0; r < 4; ++r)
        comb[qw][quad * 4 + r][df * 16 + l16] = oc[df][r];
    if (l16 == 0) {
#pragma unroll
      for (int r = 0; r < 4; ++r) combl[qw][quad * 4 + r] = lred[r];
    }
  }
  __syncthreads();
  if (g == 0) {
    float inv_l[4];
#pragma unroll
    for (int r = 0; r < 4; ++r)
      inv_l[r] = 1.f / (lred[r] + combl[qw][quad * 4 + r]);
#pragma unroll
    for (int df = 0; df < 4; ++df)
#pragma unroll
      for (int r = 0; r < 4; ++r) {
        int qrow = q0 + qw * 16 + quad * 4 + r;
        float v = oc[df][r] + comb[qw][quad * 4 + r][df * 16 + l16];
        out[(((size_t)(b * L_ + qrow)) * H_ + h) * D_ + df * 16 + l16] = v * inv_l[r];
      }
  }
}

extern "C" void kernel_launch(void* const* d_in, const int* in_sizes, int n_in,
                              void* d_out, int out_size, void* d_ws, size_t ws_size,
                              hipStream_t stream) {
  const float* qs   = (const float*)d_in[0];
  const float* ks   = (const float*)d_in[1];
  const float* vs   = (const float*)d_in[2];
  const float* qs_s = (const float*)d_in[3];
  const float* ks_s = (const float*)d_in[4];
  const float* ap   = (const float*)d_in[5];
  const float* bp   = (const float*)d_in[6];
  const float* cp   = (const float*)d_in[7];
  float* out = (float*)d_out;

  dim3 grid(B_ * H_ * (L_ / QTILE));  // 512 blocks
  dim3 block(512);                    // 8 waves: 4 q-slices x 2 K-halves
  tisa_attn_kernel<<<grid, block, 0, stream>>>(qs, ks, vs, qs_s, ks_s, ap, bp, cp, out);
}

// Round 4
// 152.239 us; speedup vs baseline: 1.6669x; 1.1151x over previous
//
#include <hip/hip_runtime.h>
#include <cmath>

typedef _Float16 half8 __attribute__((ext_vector_type(8)));
typedef _Float16 half2v __attribute__((ext_vector_type(2)));
typedef float f32x4 __attribute__((ext_vector_type(4)));
typedef float f32x2 __attribute__((ext_vector_type(2)));

#define B_ 2
#define L_ 2048
#define H_ 8
#define D_ 64
#define S_ 2
#define F_ 5
#define LUTN 512
#define LSCALE 362.03867f          // LUTN / sqrt(2)
#define LOG2E 1.44269504f
#define QSC (0.125f * LOG2E)       // folded into Q at preprocess

// ws layout (halfs): Q tiles (64x64, swizzled), K tiles (32x64, swizzled),
// VT tiles (superrow-swizzled). 4 MB each.
#define QOFF 0
#define KOFF 2097152
#define VOFF 4194304
#define WS_NEED 12582912  // bytes

// main-kernel LDS arena offsets (bytes)
#define OFF_K 0            // 4 groups x 4096 (Q tile overlays groups 0-1 pre-loop)
#define OFF_V 16384        // 4 groups x 4096
#define OFF_P 32768        // 16 waves x 1280  (16 rows x 40 halfs)
#define OFF_LUT 53248      // 513 x 8
#define OFF_KSS 57360      // 4 groups x 32 keys x 8 B
#define ARENA_SZ 59408
#define SLOTF (16 * 68 + 16)   // combine slot: O[16][68] f32 + l[16]

#define GLOBAL_LOAD_LDS16(g, l)                                                  \
  __builtin_amdgcn_global_load_lds((const __attribute__((address_space(1))) void*)(g), \
                                   (__attribute__((address_space(3))) void*)(l), 16, 0, 0)

// ---------------- preprocessing: f32 -> f16 swizzled tiles in ws ----------------
// grid 512 = (b,h,u), u in [0,32): Q-tile u (64 rows), K/V tiles 2u, 2u+1 (32 rows).
__global__ __launch_bounds__(256, 4)
void tisa_preproc(const float* __restrict__ qs, const float* __restrict__ ks,
                  const float* __restrict__ vs, _Float16* __restrict__ wsh) {
  __shared__ _Float16 Vl[64 * 72];
  const int t = threadIdx.x;
  const int u = blockIdx.x & 31;
  const int bh = blockIdx.x >> 5;
  const size_t base = ((size_t)(bh >> 3) * L_ + (size_t)u * 64) * (H_ * D_) + (size_t)(bh & 7) * D_;
  // row stride in qs/ks/vs = H_*D_ = 512 floats

  // ---- Q: 512 chunks of 8 f32 -> 8 f16, swizzled chunk c^(row&7), scaled by QSC ----
#pragma unroll
  for (int jj = 0; jj < 2; ++jj) {
    int id = t * 2 + jj;              // 0..511
    int row = id >> 3, c = id & 7;
    const float* src = qs + base + (size_t)row * 512 + c * 8;
    f32x4 x0 = ((const f32x4*)src)[0], x1 = ((const f32x4*)src)[1];
    half8 hh;
#pragma unroll
    for (int k = 0; k < 4; ++k) { hh[k] = (_Float16)(x0[k] * QSC); hh[k + 4] = (_Float16)(x1[k] * QSC); }
    *(half8*)&wsh[QOFF + ((size_t)bh * 32 + u) * 4096 + row * 64 + (c ^ (row & 7)) * 8] = hh;
  }
  // ---- K: two 32-row tiles, same chunk swizzle ----
#pragma unroll
  for (int jj = 0; jj < 2; ++jj) {
    int id = t * 2 + jj;
    int tile = id >> 8, row = (id >> 3) & 31, c = id & 7;
    const float* src = ks + base + (size_t)(tile * 32 + row) * 512 + c * 8;
    f32x4 x0 = ((const f32x4*)src)[0], x1 = ((const f32x4*)src)[1];
    half8 hh;
#pragma unroll
    for (int k = 0; k < 4; ++k) { hh[k] = (_Float16)x0[k]; hh[k + 4] = (_Float16)x1[k]; }
    *(half8*)&wsh[KOFF + ((size_t)bh * 64 + u * 2 + tile) * 2048 + row * 64 + (c ^ (row & 7)) * 8] = hh;
  }
  // ---- V: stage f16 in LDS, then transposed superrow-swizzled tiles ----
  {
    int key = t >> 2, d0 = (t & 3) * 16;
    const float* src = vs + base + (size_t)key * 512 + d0;
    f32x4 a0 = ((const f32x4*)src)[0], a1 = ((const f32x4*)src)[1];
    f32x4 a2 = ((const f32x4*)src)[2], a3 = ((const f32x4*)src)[3];
    half8 h0, h1;
#pragma unroll
    for (int k = 0; k < 4; ++k) {
      h0[k] = (_Float16)a0[k]; h0[k + 4] = (_Float16)a1[k];
      h1[k] = (_Float16)a2[k]; h1[k + 4] = (_Float16)a3[k];
    }
    *(half8*)&Vl[key * 72 + d0] = h0;
    *(half8*)&Vl[key * 72 + d0 + 8] = h1;
  }
  __syncthreads();
  // superrow s holds d=2s,2s+1; slot c' = (d&1)*4 + (k>>3); stored at c'^(s&7)
#pragma unroll
  for (int jj = 0; jj < 2; ++jj) {
    int id = t * 2 + jj;
    int tile = id >> 8, s = (id >> 3) & 31, cp = id & 7;
    int d = 2 * s + (cp >> 2), kb = (cp & 3) * 8;
    half8 hh;
#pragma unroll
    for (int j = 0; j < 8; ++j) hh[j] = Vl[(tile * 32 + kb + j) * 72 + d];
    *(half8*)&wsh[VOFF + ((size_t)bh * 64 + u * 2 + tile) * 2048 + s * 64 + (cp ^ (s & 7)) * 8] = hh;
  }
}

// ---------------- main kernel: 1024 thr = 4 q-slices x 4 K-quarters ----------------
__global__ __launch_bounds__(1024, 8)
void tisa_attn_main(const float* __restrict__ qs_s, const float* __restrict__ ks_s,
                    const float* __restrict__ ap, const float* __restrict__ bp,
                    const float* __restrict__ cp, const _Float16* __restrict__ wsh,
                    float* __restrict__ out) {
  __shared__ __align__(16) char arena[ARENA_SZ];
  f32x2* LUT2 = (f32x2*)(arena + OFF_LUT);

  const int t = threadIdx.x;
  const int lane = t & 63;
  const int w = t >> 6;       // 0..15
  const int g = w >> 2;       // K-quarter 0..3
  const int qw = w & 3;       // q-slice 0..3
  const int t2 = t & 255;     // index within group
  const int quad = lane >> 4;
  const int l16 = lane & 15;

  const int qt = blockIdx.x & 31;
  const int bh = blockIdx.x >> 5;
  const int h = bh & 7;
  const int b = bh >> 3;
  const int q0 = qt * 64;

  // ---- LUT: {(bias(d_i)-8)*log2e, slope} ----
  if (t <= LUTN) {
    float af[F_], nb[F_], cf[F_];
#pragma unroll
    for (int f = 0; f < F_; ++f) {
      af[f] = ap[h * F_ + f];
      nb[f] = -fabsf(bp[h * F_ + f]);
      cf[f] = cp[h * F_ + f];
    }
    float d0 = (float)t * (1.0f / LSCALE), d1 = (float)(t + 1) * (1.0f / LSCALE);
    float s0 = 0.f, s1 = 0.f;
#pragma unroll
    for (int f = 0; f < F_; ++f) {
      float e0 = d0 - cf[f], e1 = d1 - cf[f];
      s0 += af[f] * __expf(nb[f] * (e0 * e0));
      s1 += af[f] * __expf(nb[f] * (e1 * e1));
    }
    float v0 = (s0 - 8.0f) * LOG2E, v1 = (s1 - 8.0f) * LOG2E;
    LUT2[t] = (f32x2){v0, v1 - v0};
  }

  // q coords (pre-scaled by LSCALE) for rows qw*16 + quad*4 + r
  float qx[4], qy[4];
#pragma unroll
  for (int r = 0; r < 4; ++r) {
    int qrow = q0 + qw * 16 + quad * 4 + r;
    qx[r] = qs_s[((size_t)b * L_ + qrow) * 2 + 0] * LSCALE;
    qy[r] = qs_s[((size_t)b * L_ + qrow) * 2 + 1] * LSCALE;
  }

  const _Float16* Qt = wsh + QOFF + ((size_t)bh * 32 + qt) * 4096;
  const _Float16* Kbh = wsh + KOFF + (size_t)bh * 64 * 2048;
  const _Float16* Vbh = wsh + VOFF + (size_t)bh * 64 * 2048;

  // ---- Q tile (8 KB) -> arena[OFF_K..], waves 0..7 ----
  if (w < 8)
    GLOBAL_LOAD_LDS16(Qt + w * 512 + lane * 8, arena + OFF_K + w * 1024);
  __syncthreads();  // Q staged (+LUT built)

  half8 qA[2];
#pragma unroll
  for (int kb = 0; kb < 2; ++kb)
    qA[kb] = *(const half8*)(arena + OFF_K + (qw * 16 + l16) * 128 +
                             ((kb * 4 + quad) ^ (l16 & 7)) * 16);

  f32x4 oc[4];
#pragma unroll
  for (int df = 0; df < 4; ++df) oc[df] = (f32x4){0.f, 0.f, 0.f, 0.f};
  float lsum[4] = {0.f, 0.f, 0.f, 0.f};

  const _Float16* ksrc = Kbh + (size_t)(g * 16) * 2048 + t2 * 8;
  const _Float16* vsrc = Vbh + (size_t)(g * 16) * 2048 + t2 * 8;
  char* kdst = arena + OFF_K + g * 4096 + qw * 1024;   // wave-uniform
  char* vdst = arena + OFF_V + g * 4096 + qw * 1024;
  f32x2* kssG = (f32x2*)(arena + OFF_KSS + g * 512);
  _Float16* Pw = (_Float16*)(arena + OFF_P + w * 1280 + quad * 320 + l16 * 2);

  for (int it = 0; it < 16; ++it) {
    __syncthreads();  // prev iter's frag reads done (iter 0: qA reads done)
    GLOBAL_LOAD_LDS16(ksrc, kdst);
    GLOBAL_LOAD_LDS16(vsrc, vdst);
    ksrc += 2048; vsrc += 2048;
    if (t2 < 32) {
      f32x2 c = *(const f32x2*)(ks_s + ((size_t)b * L_ + (g * 16 + it) * 32 + t2) * 2);
      kssG[t2] = (f32x2){c.x * LSCALE, c.y * LSCALE};
    }
    __syncthreads();  // tiles + coords visible (barrier drains vmcnt)

    // ---- QK^T: 4 MFMA ----
    f32x4 acc[2];
#pragma unroll
    for (int nf = 0; nf < 2; ++nf) {
      f32x4 a = (f32x4){0.f, 0.f, 0.f, 0.f};
#pragma unroll
      for (int kb = 0; kb < 2; ++kb) {
        half8 kf = *(const half8*)(arena + OFF_K + g * 4096 + (nf * 16 + l16) * 128 +
                                   ((kb * 4 + quad) ^ (l16 & 7)) * 16);
        a = __builtin_amdgcn_mfma_f32_16x16x32_f16(qA[kb], kf, a, 0, 0, 0);
      }
      acc[nf] = a;
    }

    // ---- scores: dist LUT + exp2 (base-2 throughout), P f16 scatter ----
#pragma unroll
    for (int nf = 0; nf < 2; ++nf) {
      f32x2 kc = kssG[nf * 16 + l16];
#pragma unroll
      for (int r = 0; r < 4; ++r) {
        float dx = qx[r] - kc.x, dy = qy[r] - kc.y;
        float tt = sqrtf(fmaf(dx, dx, dy * dy));   // = dist * LSCALE
        int ii = (int)tt;
        float fr = tt - (float)ii;
        f32x2 e = LUT2[ii];
        float p = __builtin_amdgcn_exp2f(acc[nf][r] + fmaf(fr, e.y, e.x));
        acc[nf][r] = p;
        lsum[r] += p;
        Pw[r * 40 + nf * 16] = (_Float16)p;   // P[qrow=quad*4+r][key=nf*16+l16]
      }
    }

    // ---- PV: 4 MFMA (K=32 exactly); same-wave DS ordering, no barrier ----
    half8 pa = *(const half8*)(arena + OFF_P + w * 1280 + l16 * 80 + quad * 16);
#pragma unroll
    for (int df = 0; df < 4; ++df) {
      half8 vf = *(const half8*)(arena + OFF_V + g * 4096 + (l16 >> 1) * 128 + df * 1024 +
                                 ((((l16 & 1) * 4 + quad) ^ ((l16 >> 1) & 7)) * 16));
      oc[df] = __builtin_amdgcn_mfma_f32_16x16x32_f16(pa, vf, oc[df], 0, 0, 0);
    }
  }

  // ---- combine 4 K-quarters via LDS tree ----
  float lred[4];
#pragma unroll
  for (int r = 0; r < 4; ++r) {
    float s = lsum[r];
    s += __shfl_xor(s, 1);
    s += __shfl_xor(s, 2);
    s += __shfl_xor(s, 4);
    s += __shfl_xor(s, 8);
    lred[r] = s;
  }
  __syncthreads();  // all loop LDS reads done; arena reusable
  float* slots = (float*)arena;
  if (g >= 2) {
    float* sl = slots + ((g - 2) * 4 + qw) * SLOTF;
#pragma unroll
    for (int df = 0; df < 4; ++df)
#pragma unroll
      for (int r = 0; r < 4; ++r)
        sl[(quad * 4 + r) * 68 + df * 16 + l16] = oc[df][r];
    if (l16 == 0) {
#pragma unroll
      for (int r = 0; r < 4; ++r) sl[16 * 68 + quad * 4 + r] = lred[r];
    }
  }
  __syncthreads();
  if (g < 2) {
    float* sl = slots + (g * 4 + qw) * SLOTF;   // g0<-slot(g2), g1<-slot(g3)
#pragma unroll
    for (int df = 0; df < 4; ++df)
#pragma unroll
      for (int r = 0; r < 4; ++r)
        oc[df][r] += sl[(quad * 4 + r) * 68 + df * 16 + l16];
#pragma unroll
    for (int r = 0; r < 4; ++r) lred[r] += sl[16 * 68 + quad * 4 + r];
  }
  if (g == 1) {  // write combined back into same slot (same-wave, in-order)
    float* sl = slots + (4 + qw) * SLOTF;
#pragma unroll
    for (int df = 0; df < 4; ++df)
#pragma unroll
      for (int r = 0; r < 4; ++r)
        sl[(quad * 4 + r) * 68 + df * 16 + l16] = oc[df][r];
    if (l16 == 0) {
#pragma unroll
      for (int r = 0; r < 4; ++r) sl[16 * 68 + quad * 4 + r] = lred[r];
    }
  }
  __syncthreads();
  if (g == 0) {
    float* sl = slots + (4 + qw) * SLOTF;
    float inv_l[4];
#pragma unroll
    for (int r = 0; r < 4; ++r)
      inv_l[r] = 1.f / (lred[r] + sl[16 * 68 + quad * 4 + r]);
#pragma unroll
    for (int df = 0; df < 4; ++df)
#pragma unroll
      for (int r = 0; r < 4; ++r) {
        int qrow = q0 + qw * 16 + quad * 4 + r;
        float v = oc[df][r] + sl[(quad * 4 + r) * 68 + df * 16 + l16];
        out[((size_t)(b * L_ + qrow)) * (H_ * D_) + h * D_ + df * 16 + l16] = v * inv_l[r];
      }
  }
}

// ---------------- fallback (R3 kernel) if ws too small ----------------
#define KSTR 72
#define PH 72
__global__ __launch_bounds__(512, 4)
void tisa_attn_fallback(const float* __restrict__ qs, const float* __restrict__ ks,
                        const float* __restrict__ vs, const float* __restrict__ qs_s,
                        const float* __restrict__ ks_s, const float* __restrict__ ap,
                        const float* __restrict__ bp, const float* __restrict__ cp,
                        float* __restrict__ out) {
  __shared__ _Float16 Ks[2][64 * KSTR];
  __shared__ _Float16 VT[2][D_ * KSTR];
  __shared__ _Float16 Pf[8][16 * PH];
  __shared__ float kss2[2][64 * 2];
  __shared__ f32x2 LUT2s[LUTN + 1];
  __shared__ float comb[4][16][64];
  __shared__ float combl[4][16];

  const int t = threadIdx.x;
  const int lane = t & 63;
  const int w = t >> 6;
  const int g = w >> 2;
  const int qw = w & 3;
  const int t2 = t & 255;
  const int quad = lane >> 4;
  const int l16 = lane & 15;
  const int qt = blockIdx.x & 31;
  const int bh = blockIdx.x >> 5;
  const int h = bh & 7;
  const int b = bh >> 3;
  const int q0 = qt * 64;

  float af[F_], nb[F_], cf[F_];
#pragma unroll
  for (int f = 0; f < F_; ++f) {
    af[f] = ap[h * F_ + f];
    nb[f] = -fabsf(bp[h * F_ + f]);
    cf[f] = cp[h * F_ + f];
  }
  for (int i = t; i <= LUTN; i += 512) {
    float d0 = (float)i * (1.0f / LSCALE), d1 = (float)(i + 1) * (1.0f / LSCALE);
    float s0 = 0.f, s1 = 0.f;
#pragma unroll
    for (int f = 0; f < F_; ++f) {
      float e0 = d0 - cf[f], e1 = d1 - cf[f];
      s0 += af[f] * __expf(nb[f] * (e0 * e0));
      s1 += af[f] * __expf(nb[f] * (e1 * e1));
    }
    LUT2s[i] = (f32x2){s0 - 8.0f, s1 - 8.0f};
  }
  float qx[4], qy[4];
#pragma unroll
  for (int r = 0; r < 4; ++r) {
    int qrow = q0 + qw * 16 + quad * 4 + r;
    qx[r] = qs_s[(b * L_ + qrow) * S_ + 0];
    qy[r] = qs_s[(b * L_ + qrow) * S_ + 1];
  }
  if (t < 256) {
    const int row = t >> 2, dc = (t & 3) * 16;
    const float* src = qs + (((size_t)(b * L_ + q0 + row)) * H_ + h) * D_ + dc;
    const f32x4* s4 = (const f32x4*)src;
    f32x4 v0 = s4[0], v1 = s4[1], v2 = s4[2], v3 = s4[3];
    half8 w0, w1;
#pragma unroll
    for (int u = 0; u < 4; ++u) {
      w0[u] = (_Float16)(v0[u] * 0.125f); w0[u + 4] = (_Float16)(v1[u] * 0.125f);
      w1[u] = (_Float16)(v2[u] * 0.125f); w1[u + 4] = (_Float16)(v3[u] * 0.125f);
    }
    *(half8*)&Ks[0][row * KSTR + dc] = w0;
    *(half8*)&Ks[0][row * KSTR + dc + 8] = w1;
  }
  __syncthreads();
  half8 qA[2];
#pragma unroll
  for (int kb = 0; kb < 2; ++kb)
    qA[kb] = *(const half8*)&Ks[0][(qw * 16 + l16) * KSTR + kb * 32 + quad * 8];
  f32x4 oc[4];
#pragma unroll
  for (int df = 0; df < 4; ++df) oc[df] = (f32x4){0.f, 0.f, 0.f, 0.f};
  float l_r[4] = {0.f, 0.f, 0.f, 0.f};

  for (int it = 0; it < 16; ++it) {
    const int k0 = (g * 16 + it) * 64;
    __syncthreads();
    {
      const int row = t2 >> 2, dc = (t2 & 3) * 16;
      const float* src = ks + (((size_t)(b * L_ + k0 + row)) * H_ + h) * D_ + dc;
      const f32x4* s4 = (const f32x4*)src;
      f32x4 v0 = s4[0], v1 = s4[1], v2 = s4[2], v3 = s4[3];
      half8 w0, w1;
#pragma unroll
      for (int u = 0; u < 4; ++u) {
        w0[u] = (_Float16)v0[u]; w0[u + 4] = (_Float16)v1[u];
        w1[u] = (_Float16)v2[u]; w1[u + 4] = (_Float16)v3[u];
      }
      *(half8*)&Ks[g][row * KSTR + dc] = w0;
      *(half8*)&Ks[g][row * KSTR + dc + 8] = w1;
    }
    {
      const int kk = (t2 & 31) * 2, dg = (t2 >> 5) * 8;
      const float* s0 = vs + (((size_t)(b * L_ + k0 + kk)) * H_ + h) * D_ + dg;
      const float* s1 = s0 + H_ * D_;
      f32x4 a0 = ((const f32x4*)s0)[0], a1 = ((const f32x4*)s0)[1];
      f32x4 b0 = ((const f32x4*)s1)[0], b1 = ((const f32x4*)s1)[1];
#pragma unroll
      for (int u = 0; u < 4; ++u) {
        half2v p0 = {(_Float16)a0[u], (_Float16)b0[u]};
        *(half2v*)&VT[g][(dg + u) * KSTR + kk] = p0;
        half2v p1 = {(_Float16)a1[u], (_Float16)b1[u]};
        *(half2v*)&VT[g][(dg + 4 + u) * KSTR + kk] = p1;
      }
    }
    if (t2 < 128) kss2[g][t2] = ks_s[((size_t)(b * L_) + k0 + (t2 >> 1)) * S_ + (t2 & 1)];
    __syncthreads();
    f32x4 acc[4];
#pragma unroll
    for (int nf = 0; nf < 4; ++nf) {
      f32x4 a = (f32x4){0.f, 0.f, 0.f, 0.f};
#pragma unroll
      for (int kb = 0; kb < 2; ++kb) {
        half8 kf = *(const half8*)&Ks[g][(nf * 16 + l16) * KSTR + kb * 32 + quad * 8];
        a = __builtin_amdgcn_mfma_f32_16x16x32_f16(qA[kb], kf, a, 0, 0, 0);
      }
      acc[nf] = a;
    }
#pragma unroll
    for (int nf = 0; nf < 4; ++nf) {
      float kx = kss2[g][(nf * 16 + l16) * 2 + 0];
      float ky = kss2[g][(nf * 16 + l16) * 2 + 1];
#pragma unroll
      for (int r = 0; r < 4; ++r) {
        float dx = qx[r] - kx, dy = qy[r] - ky;
        float dist = sqrtf(fmaf(dx, dx, dy * dy));
        float tt = dist * LSCALE;
        int ii = (int)tt;
        float fr = tt - (float)ii;
        f32x2 lh = LUT2s[ii];
        float p = __expf(acc[nf][r] + fmaf(fr, lh.y - lh.x, lh.x));
        acc[nf][r] = p;
      }
    }
#pragma unroll
    for (int r = 0; r < 4; ++r)
      l_r[r] += (acc[0][r] + acc[1][r]) + (acc[2][r] + acc[3][r]);
#pragma unroll
    for (int nf = 0; nf < 4; ++nf)
#pragma unroll
      for (int r = 0; r < 4; ++r)
        Pf[w][(quad * 4 + r) * PH + nf * 16 + l16] = (_Float16)acc[nf][r];
#pragma unroll
    for (int kb = 0; kb < 2; ++kb) {
      half8 pa = *(const half8*)&Pf[w][l16 * PH + kb * 32 + quad * 8];
#pragma unroll
      for (int df = 0; df < 4; ++df) {
        half8 vf = *(const half8*)&VT[g][(df * 16 + l16) * KSTR + kb * 32 + quad * 8];
        oc[df] = __builtin_amdgcn_mfma_f32_16x16x32_f16(pa, vf, oc[df], 0, 0, 0);
      }
    }
  }
  __syncthreads();
  float lred[4];
#pragma unroll
  for (int r = 0; r < 4; ++r) {
    float s = l_r[r];
    s += __shfl_xor(s, 1); s += __shfl_xor(s, 2);
    s += __shfl_xor(s, 4); s += __shfl_xor(s, 8);
    lred[r] = s;
  }
  if (g == 1) {
#pragma unroll
    for (int df = 0; df < 4; ++df)
#pragma unroll
      for (int r = 0; r < 4; ++r)
        comb[qw][quad * 4 + r][df * 16 + l16] = oc[df][r];
    if (l16 == 0) {
#pragma unroll
      for (int r = 0; r < 4; ++r) combl[qw][quad * 4 + r] = lred[r];
    }
  }
  __syncthreads();
  if (g == 0) {
    float inv_l[4];
#pragma unroll
    for (int r = 0; r < 4; ++r)
      inv_l[r] = 1.f / (lred[r] + combl[qw][quad * 4 + r]);
#pragma unroll
    for (int df = 0; df < 4; ++df)
#pragma unroll
      for (int r = 0; r < 4; ++r) {
        int qrow = q0 + qw * 16 + quad * 4 + r;
        float v = oc[df][r] + comb[qw][quad * 4 + r][df * 16 + l16];
        out[(((size_t)(b * L_ + qrow)) * H_ + h) * D_ + df * 16 + l16] = v * inv_l[r];
      }
  }
}

extern "C" void kernel_launch(void* const* d_in, const int* in_sizes, int n_in,
                              void* d_out, int out_size, void* d_ws, size_t ws_size,
                              hipStream_t stream) {
  const float* qs = (const float*)d_in[0];
  const float* ks = (const float*)d_in[1];
  const float* vs = (const float*)d_in[2];
  const float* qs_s = (const float*)d_in[3];
  const float* ks_s = (const float*)d_in[4];
  const float* ap = (const float*)d_in[5];
  const float* bp = (const float*)d_in[6];
  const float* cp = (const float*)d_in[7];
  float* out = (float*)d_out;

  if (ws_size >= (size_t)WS_NEED) {
    _Float16* wsh = (_Float16*)d_ws;
    tisa_preproc<<<dim3(512), dim3(256), 0, stream>>>(qs, ks, vs, wsh);
    tisa_attn_main<<<dim3(512), dim3(1024), 0, stream>>>(qs_s, ks_s, ap, bp, cp, wsh, out);
  } else {
    tisa_attn_fallback<<<dim3(512), dim3(512), 0, stream>>>(qs, ks, vs, qs_s, ks_s, ap, bp, cp, out);
  }
}

// Round 6
// 150.794 us; speedup vs baseline: 1.6829x; 1.0096x over previous
//
#include <hip/hip_runtime.h>
#include <cmath>

typedef _Float16 half8 __attribute__((ext_vector_type(8)));
typedef _Float16 half2v __attribute__((ext_vector_type(2)));
typedef float f32x4 __attribute__((ext_vector_type(4)));
typedef float f32x2 __attribute__((ext_vector_type(2)));

#define B_ 2
#define L_ 2048
#define H_ 8
#define D_ 64
#define S_ 2
#define F_ 5
#define LUTN 2048
#define LSCALE 1448.1547f          // LUTN / sqrt(2)
#define LOG2E 1.44269504f
#define QSC (0.125f * LOG2E)       // folded into Q at preprocess

// ws layout: Q tiles (64x64 f16, swizzled), K tiles (32x64 f16, swizzled),
// VT tiles (superrow-swizzled f16), then pre-scaled ks_s coords (f32).
#define QOFF 0            // halfs
#define KOFF 2097152      // halfs
#define VOFF 4194304      // halfs
#define SOFFH 6291456     // halfs -> (float*)(wsh + SOFFH)
#define WS_NEED 12615680  // bytes

// main-kernel LDS arena offsets (bytes)
#define OFF_K 0            // 4 groups x 4096 (Q tile overlays groups 0-1 pre-loop)
#define OFF_V 16384        // 4 groups x 4096
#define OFF_P 32768        // 16 waves x 1280  (16 rows x 40 halfs)
#define OFF_LUT 53248      // 2049 x 4 (+pad) = 8208
#define OFF_KSS 61456      // 4 groups x 256 B (32 keys x f32x2) -> ends at 62480
#define ARENA_SZ 62480
#define SLOTF (16 * 68 + 16)   // combine slot: O[16][68] f32 + l[16]

#define GLOBAL_LOAD_LDS16(g, l)                                                  \
  __builtin_amdgcn_global_load_lds((const __attribute__((address_space(1))) void*)(g), \
                                   (__attribute__((address_space(3))) void*)(l), 16, 0, 0)

// ---------------- preprocessing: f32 -> f16 swizzled tiles in ws ----------------
// grid 512 = (b,h,u), u in [0,32): Q-tile u (64 rows), K/V tiles 2u, 2u+1 (32 rows).
__global__ __launch_bounds__(256, 4)
void tisa_preproc(const float* __restrict__ qs, const float* __restrict__ ks,
                  const float* __restrict__ vs, const float* __restrict__ ks_s,
                  _Float16* __restrict__ wsh) {
  __shared__ _Float16 Vl[64 * 72];
  const int t = threadIdx.x;
  const int u = blockIdx.x & 31;
  const int bh = blockIdx.x >> 5;
  const size_t base = ((size_t)(bh >> 3) * L_ + (size_t)u * 64) * (H_ * D_) + (size_t)(bh & 7) * D_;

  // ---- Q: 512 chunks of 8 f32 -> 8 f16, swizzled chunk c^(row&7), scaled by QSC ----
#pragma unroll
  for (int jj = 0; jj < 2; ++jj) {
    int id = t * 2 + jj;              // 0..511
    int row = id >> 3, c = id & 7;
    const float* src = qs + base + (size_t)row * 512 + c * 8;
    f32x4 x0 = ((const f32x4*)src)[0], x1 = ((const f32x4*)src)[1];
    half8 hh;
#pragma unroll
    for (int k = 0; k < 4; ++k) { hh[k] = (_Float16)(x0[k] * QSC); hh[k + 4] = (_Float16)(x1[k] * QSC); }
    *(half8*)&wsh[QOFF + ((size_t)bh * 32 + u) * 4096 + row * 64 + (c ^ (row & 7)) * 8] = hh;
  }
  // ---- K: two 32-row tiles, same chunk swizzle ----
#pragma unroll
  for (int jj = 0; jj < 2; ++jj) {
    int id = t * 2 + jj;
    int tile = id >> 8, row = (id >> 3) & 31, c = id & 7;
    const float* src = ks + base + (size_t)(tile * 32 + row) * 512 + c * 8;
    f32x4 x0 = ((const f32x4*)src)[0], x1 = ((const f32x4*)src)[1];
    half8 hh;
#pragma unroll
    for (int k = 0; k < 4; ++k) { hh[k] = (_Float16)x0[k]; hh[k + 4] = (_Float16)x1[k]; }
    *(half8*)&wsh[KOFF + ((size_t)bh * 64 + u * 2 + tile) * 2048 + row * 64 + (c ^ (row & 7)) * 8] = hh;
  }
  // ---- scaled ks_s coords (h==0 blocks only; 64 keys = 128 floats) ----
  if ((bh & 7) == 0 && t < 32) {
    const int b = bh >> 3;
    const float* src = ks_s + ((size_t)b * L_ + u * 64) * 2 + t * 4;
    float* dst = (float*)(wsh + SOFFH) + ((size_t)b * L_ + u * 64) * 2 + t * 4;
    f32x4 x = *(const f32x4*)src;
    x *= LSCALE;
    *(f32x4*)dst = x;
  }
  // ---- V: stage f16 in LDS, then transposed superrow-swizzled tiles ----
  {
    int key = t >> 2, d0 = (t & 3) * 16;
    const float* src = vs + base + (size_t)key * 512 + d0;
    f32x4 a0 = ((const f32x4*)src)[0], a1 = ((const f32x4*)src)[1];
    f32x4 a2 = ((const f32x4*)src)[2], a3 = ((const f32x4*)src)[3];
    half8 h0, h1;
#pragma unroll
    for (int k = 0; k < 4; ++k) {
      h0[k] = (_Float16)a0[k]; h0[k + 4] = (_Float16)a1[k];
      h1[k] = (_Float16)a2[k]; h1[k + 4] = (_Float16)a3[k];
    }
    *(half8*)&Vl[key * 72 + d0] = h0;
    *(half8*)&Vl[key * 72 + d0 + 8] = h1;
  }
  __syncthreads();
  // superrow s holds d=2s,2s+1; slot c' = (d&1)*4 + (k>>3); stored at c'^(s&7)
#pragma unroll
  for (int jj = 0; jj < 2; ++jj) {
    int id = t * 2 + jj;
    int tile = id >> 8, s = (id >> 3) & 31, cp = id & 7;
    int d = 2 * s + (cp >> 2), kb = (cp & 3) * 8;
    half8 hh;
#pragma unroll
    for (int j = 0; j < 8; ++j) hh[j] = Vl[(tile * 32 + kb + j) * 72 + d];
    *(half8*)&wsh[VOFF + ((size_t)bh * 64 + u * 2 + tile) * 2048 + s * 64 + (cp ^ (s & 7)) * 8] = hh;
  }
}

// ---------------- main kernel: 1024 thr = 4 q-slices x 4 K-quarters ----------------
__global__ __launch_bounds__(1024, 8)
void tisa_attn_main(const float* __restrict__ qs_s, const float* __restrict__ ap,
                    const float* __restrict__ bp, const float* __restrict__ cp,
                    const _Float16* __restrict__ wsh, float* __restrict__ out) {
  __shared__ __align__(16) char arena[ARENA_SZ];
  float* LUT = (float*)(arena + OFF_LUT);

  const int t = threadIdx.x;
  const int lane = t & 63;
  const int w = t >> 6;       // 0..15
  const int g = w >> 2;       // K-quarter 0..3
  const int qw = w & 3;       // q-slice 0..3
  const int t2 = t & 255;     // index within group
  const int quad = lane >> 4;
  const int l16 = lane & 15;

  const int qt = blockIdx.x & 31;
  const int bh = blockIdx.x >> 5;
  const int h = bh & 7;
  const int b = bh >> 3;
  const int q0 = qt * 64;

  // ---- LUT (nearest-neighbor, midpoint-sampled): ((bias-8)*log2e) at d=(i+0.5)/LSCALE ----
  {
    float af[F_], nb[F_], cf[F_];
#pragma unroll
    for (int f = 0; f < F_; ++f) {
      af[f] = ap[h * F_ + f];
      nb[f] = -fabsf(bp[h * F_ + f]);
      cf[f] = cp[h * F_ + f];
    }
    for (int i = t; i <= LUTN; i += 1024) {
      float d = ((float)i + 0.5f) * (1.0f / LSCALE);
      float s = 0.f;
#pragma unroll
      for (int f = 0; f < F_; ++f) {
        float e = d - cf[f];
        s += af[f] * __expf(nb[f] * (e * e));
      }
      LUT[i] = (s - 8.0f) * LOG2E;
    }
  }

  // q coords (pre-scaled by LSCALE) for rows qw*16 + quad*4 + r
  float qx[4], qy[4];
#pragma unroll
  for (int r = 0; r < 4; ++r) {
    int qrow = q0 + qw * 16 + quad * 4 + r;
    qx[r] = qs_s[((size_t)b * L_ + qrow) * 2 + 0] * LSCALE;
    qy[r] = qs_s[((size_t)b * L_ + qrow) * 2 + 1] * LSCALE;
  }

  const _Float16* Qt = wsh + QOFF + ((size_t)bh * 32 + qt) * 4096;
  const _Float16* Kbh = wsh + KOFF + (size_t)bh * 64 * 2048;
  const _Float16* Vbh = wsh + VOFF + (size_t)bh * 64 * 2048;
  const float* wsS = (const float*)(wsh + SOFFH);

  // ---- Q tile (8 KB) -> arena[OFF_K..], waves 0..7 ----
  if (w < 8)
    GLOBAL_LOAD_LDS16(Qt + w * 512 + lane * 8, arena + OFF_K + w * 1024);
  __syncthreads();  // Q staged (+LUT built)

  half8 qA[2];
#pragma unroll
  for (int kb = 0; kb < 2; ++kb)
    qA[kb] = *(const half8*)(arena + OFF_K + (qw * 16 + l16) * 128 +
                             ((kb * 4 + quad) ^ (l16 & 7)) * 16);

  f32x4 oc[4];
#pragma unroll
  for (int df = 0; df < 4; ++df) oc[df] = (f32x4){0.f, 0.f, 0.f, 0.f};
  f32x4 lsacc = (f32x4){0.f, 0.f, 0.f, 0.f};
  half8 onesv;
#pragma unroll
  for (int j = 0; j < 8; ++j) onesv[j] = (_Float16)1.0f;

  const _Float16* ksrc = Kbh + (size_t)(g * 16) * 2048 + t2 * 8;
  const _Float16* vsrc = Vbh + (size_t)(g * 16) * 2048 + t2 * 8;
  const f32x2* ssrc = (const f32x2*)(wsS + ((size_t)b * L_ + g * 512) * 2);  // pre-scaled coords
  char* kdst = arena + OFF_K + g * 4096 + qw * 1024;   // wave-uniform
  char* vdst = arena + OFF_V + g * 4096 + qw * 1024;
  f32x2* kssG = (f32x2*)(arena + OFF_KSS + g * 256);
  _Float16* Pw = (_Float16*)(arena + OFF_P + w * 1280 + quad * 320 + l16 * 2);

  for (int it = 0; it < 16; ++it) {
    __syncthreads();  // prev iter's frag reads done (iter 0: qA reads done)
    GLOBAL_LOAD_LDS16(ksrc, kdst);
    GLOBAL_LOAD_LDS16(vsrc, vdst);
    ksrc += 2048; vsrc += 2048;
    if (t2 < 32) kssG[t2] = ssrc[t2];   // plain copy (coords pre-scaled in ws)
    ssrc += 32;
    __syncthreads();  // tiles + coords visible (barrier drains vmcnt/lgkmcnt)

    // ---- QK^T: 4 MFMA ----
    f32x4 acc[2];
#pragma unroll
    for (int nf = 0; nf < 2; ++nf) {
      f32x4 a = (f32x4){0.f, 0.f, 0.f, 0.f};
#pragma unroll
      for (int kb = 0; kb < 2; ++kb) {
        half8 kf = *(const half8*)(arena + OFF_K + g * 4096 + (nf * 16 + l16) * 128 +
                                   ((kb * 4 + quad) ^ (l16 & 7)) * 16);
        a = __builtin_amdgcn_mfma_f32_16x16x32_f16(qA[kb], kf, a, 0, 0, 0);
      }
      acc[nf] = a;
    }

    // ---- scores: dist -> nearest-LUT -> exp2; P f16 scatter ----
#pragma unroll
    for (int nf = 0; nf < 2; ++nf) {
      f32x2 kc = kssG[nf * 16 + l16];
#pragma unroll
      for (int r = 0; r < 4; ++r) {
        float dx = qx[r] - kc.x, dy = qy[r] - kc.y;
        float tt = sqrtf(fmaf(dx, dx, dy * dy));   // = dist * LSCALE
        int ii = (int)tt;
        float p = __builtin_amdgcn_exp2f(acc[nf][r] + LUT[ii]);
        acc[nf][r] = p;
        Pw[r * 40 + nf * 16] = (_Float16)p;   // P[qrow=quad*4+r][key=nf*16+l16]
      }
    }

    // ---- PV + row-sum via ones-MFMA; same-wave DS ordering, no barrier ----
    half8 pa = *(const half8*)(arena + OFF_P + w * 1280 + l16 * 80 + quad * 16);
    lsacc = __builtin_amdgcn_mfma_f32_16x16x32_f16(pa, onesv, lsacc, 0, 0, 0);
#pragma unroll
    for (int df = 0; df < 4; ++df) {
      half8 vf = *(const half8*)(arena + OFF_V + g * 4096 + (l16 >> 1) * 128 + df * 1024 +
                                 ((((l16 & 1) * 4 + quad) ^ ((l16 >> 1) & 7)) * 16));
      oc[df] = __builtin_amdgcn_mfma_f32_16x16x32_f16(pa, vf, oc[df], 0, 0, 0);
    }
  }

  // ---- combine 4 K-quarters via LDS tree (row sums already reduced by ones-MFMA) ----
  float lred[4];
#pragma unroll
  for (int r = 0; r < 4; ++r) lred[r] = lsacc[r];
  __syncthreads();  // all loop LDS reads done; arena reusable
  float* slots = (float*)arena;
  if (g >= 2) {
    float* sl = slots + ((g - 2) * 4 + qw) * SLOTF;
#pragma unroll
    for (int df = 0; df < 4; ++df)
#pragma unroll
      for (int r = 0; r < 4; ++r)
        sl[(quad * 4 + r) * 68 + df * 16 + l16] = oc[df][r];
    if (l16 == 0) {
#pragma unroll
      for (int r = 0; r < 4; ++r) sl[16 * 68 + quad * 4 + r] = lred[r];
    }
  }
  __syncthreads();
  if (g < 2) {
    float* sl = slots + (g * 4 + qw) * SLOTF;   // g0<-slot(g2), g1<-slot(g3)
#pragma unroll
    for (int df = 0; df < 4; ++df)
#pragma unroll
      for (int r = 0; r < 4; ++r)
        oc[df][r] += sl[(quad * 4 + r) * 68 + df * 16 + l16];
#pragma unroll
    for (int r = 0; r < 4; ++r) lred[r] += sl[16 * 68 + quad * 4 + r];
  }
  if (g == 1) {  // write combined back into same slot (same-wave, in-order)
    float* sl = slots + (4 + qw) * SLOTF;
#pragma unroll
    for (int df = 0; df < 4; ++df)
#pragma unroll
      for (int r = 0; r < 4; ++r)
        sl[(quad * 4 + r) * 68 + df * 16 + l16] = oc[df][r];
    if (l16 == 0) {
#pragma unroll
      for (int r = 0; r < 4; ++r) sl[16 * 68 + quad * 4 + r] = lred[r];
    }
  }
  __syncthreads();
  if (g == 0) {
    float* sl = slots + (4 + qw) * SLOTF;
    float inv_l[4];
#pragma unroll
    for (int r = 0; r < 4; ++r)
      inv_l[r] = 1.f / (lred[r] + sl[16 * 68 + quad * 4 + r]);
#pragma unroll
    for (int df = 0; df < 4; ++df)
#pragma unroll
      for (int r = 0; r < 4; ++r) {
        int qrow = q0 + qw * 16 + quad * 4 + r;
        float v = oc[df][r] + sl[(quad * 4 + r) * 68 + df * 16 + l16];
        out[((size_t)(b * L_ + qrow)) * (H_ * D_) + h * D_ + df * 16 + l16] = v * inv_l[r];
      }
  }
}

// ---------------- fallback (R3 kernel) if ws too small ----------------
#define KSTR 72
#define PH 72
#define FLUTN 512
#define FLSCALE 362.03867f
__global__ __launch_bounds__(512, 4)
void tisa_attn_fallback(const float* __restrict__ qs, const float* __restrict__ ks,
                        const float* __restrict__ vs, const float* __restrict__ qs_s,
                        const float* __restrict__ ks_s, const float* __restrict__ ap,
                        const float* __restrict__ bp, const float* __restrict__ cp,
                        float* __restrict__ out) {
  __shared__ _Float16 Ks[2][64 * KSTR];
  __shared__ _Float16 VT[2][D_ * KSTR];
  __shared__ _Float16 Pf[8][16 * PH];
  __shared__ float kss2[2][64 * 2];
  __shared__ f32x2 LUT2s[FLUTN + 1];
  __shared__ float comb[4][16][64];
  __shared__ float combl[4][16];

  const int t = threadIdx.x;
  const int lane = t & 63;
  const int w = t >> 6;
  const int g = w >> 2;
  const int qw = w & 3;
  const int t2 = t & 255;
  const int quad = lane >> 4;
  const int l16 = lane & 15;
  const int qt = blockIdx.x & 31;
  const int bh = blockIdx.x >> 5;
  const int h = bh & 7;
  const int b = bh >> 3;
  const int q0 = qt * 64;

  float af[F_], nb[F_], cf[F_];
#pragma unroll
  for (int f = 0; f < F_; ++f) {
    af[f] = ap[h * F_ + f];
    nb[f] = -fabsf(bp[h * F_ + f]);
    cf[f] = cp[h * F_ + f];
  }
  for (int i = t; i <= FLUTN; i += 512) {
    float d0 = (float)i * (1.0f / FLSCALE), d1 = (float)(i + 1) * (1.0f / FLSCALE);
    float s0 = 0.f, s1 = 0.f;
#pragma unroll
    for (int f = 0; f < F_; ++f) {
      float e0 = d0 - cf[f], e1 = d1 - cf[f];
      s0 += af[f] * __expf(nb[f] * (e0 * e0));
      s1 += af[f] * __expf(nb[f] * (e1 * e1));
    }
    LUT2s[i] = (f32x2){s0 - 8.0f, s1 - 8.0f};
  }
  float qx[4], qy[4];
#pragma unroll
  for (int r = 0; r < 4; ++r) {
    int qrow = q0 + qw * 16 + quad * 4 + r;
    qx[r] = qs_s[(b * L_ + qrow) * S_ + 0];
    qy[r] = qs_s[(b * L_ + qrow) * S_ + 1];
  }
  if (t < 256) {
    const int row = t >> 2, dc = (t & 3) * 16;
    const float* src = qs + (((size_t)(b * L_ + q0 + row)) * H_ + h) * D_ + dc;
    const f32x4* s4 = (const f32x4*)src;
    f32x4 v0 = s4[0], v1 = s4[1], v2 = s4[2], v3 = s4[3];
    half8 w0, w1;
#pragma unroll
    for (int u = 0; u < 4; ++u) {
      w0[u] = (_Float16)(v0[u] * 0.125f); w0[u + 4] = (_Float16)(v1[u] * 0.125f);
      w1[u] = (_Float16)(v2[u] * 0.125f); w1[u + 4] = (_Float16)(v3[u] * 0.125f);
    }
    *(half8*)&Ks[0][row * KSTR + dc] = w0;
    *(half8*)&Ks[0][row * KSTR + dc + 8] = w1;
  }
  __syncthreads();
  half8 qA[2];
#pragma unroll
  for (int kb = 0; kb < 2; ++kb)
    qA[kb] = *(const half8*)&Ks[0][(qw * 16 + l16) * KSTR + kb * 32 + quad * 8];
  f32x4 oc[4];
#pragma unroll
  for (int df = 0; df < 4; ++df) oc[df] = (f32x4){0.f, 0.f, 0.f, 0.f};
  float l_r[4] = {0.f, 0.f, 0.f, 0.f};

  for (int it = 0; it < 16; ++it) {
    const int k0 = (g * 16 + it) * 64;
    __syncthreads();
    {
      const int row = t2 >> 2, dc = (t2 & 3) * 16;
      const float* src = ks + (((size_t)(b * L_ + k0 + row)) * H_ + h) * D_ + dc;
      const f32x4* s4 = (const f32x4*)src;
      f32x4 v0 = s4[0], v1 = s4[1], v2 = s4[2], v3 = s4[3];
      half8 w0, w1;
#pragma unroll
      for (int u = 0; u < 4; ++u) {
        w0[u] = (_Float16)v0[u]; w0[u + 4] = (_Float16)v1[u];
        w1[u] = (_Float16)v2[u]; w1[u + 4] = (_Float16)v3[u];
      }
      *(half8*)&Ks[g][row * KSTR + dc] = w0;
      *(half8*)&Ks[g][row * KSTR + dc + 8] = w1;
    }
    {
      const int kk = (t2 & 31) * 2, dg = (t2 >> 5) * 8;
      const float* s0 = vs + (((size_t)(b * L_ + k0 + kk)) * H_ + h) * D_ + dg;
      const float* s1 = s0 + H_ * D_;
      f32x4 a0 = ((const f32x4*)s0)[0], a1 = ((const f32x4*)s0)[1];
      f32x4 b0 = ((const f32x4*)s1)[0], b1 = ((const f32x4*)s1)[1];
#pragma unroll
      for (int u = 0; u < 4; ++u) {
        half2v p0 = {(_Float16)a0[u], (_Float16)b0[u]};
        *(half2v*)&VT[g][(dg + u) * KSTR + kk] = p0;
        half2v p1 = {(_Float16)a1[u], (_Float16)b1[u]};
        *(half2v*)&VT[g][(dg + 4 + u) * KSTR + kk] = p1;
      }
    }
    if (t2 < 128) kss2[g][t2] = ks_s[((size_t)(b * L_) + k0 + (t2 >> 1)) * S_ + (t2 & 1)];
    __syncthreads();
    f32x4 acc[4];
#pragma unroll
    for (int nf = 0; nf < 4; ++nf) {
      f32x4 a = (f32x4){0.f, 0.f, 0.f, 0.f};
#pragma unroll
      for (int kb = 0; kb < 2; ++kb) {
        half8 kf = *(const half8*)&Ks[g][(nf * 16 + l16) * KSTR + kb * 32 + quad * 8];
        a = __builtin_amdgcn_mfma_f32_16x16x32_f16(qA[kb], kf, a, 0, 0, 0);
      }
      acc[nf] = a;
    }
#pragma unroll
    for (int nf = 0; nf < 4; ++nf) {
      float kx = kss2[g][(nf * 16 + l16) * 2 + 0];
      float ky = kss2[g][(nf * 16 + l16) * 2 + 1];
#pragma unroll
      for (int r = 0; r < 4; ++r) {
        float dx = qx[r] - kx, dy = qy[r] - ky;
        float dist = sqrtf(fmaf(dx, dx, dy * dy));
        float tt = dist * FLSCALE;
        int ii = (int)tt;
        float fr = tt - (float)ii;
        f32x2 lh = LUT2s[ii];
        float p = __expf(acc[nf][r] + fmaf(fr, lh.y - lh.x, lh.x));
        acc[nf][r] = p;
      }
    }
#pragma unroll
    for (int r = 0; r < 4; ++r)
      l_r[r] += (acc[0][r] + acc[1][r]) + (acc[2][r] + acc[3][r]);
#pragma unroll
    for (int nf = 0; nf < 4; ++nf)
#pragma unroll
      for (int r = 0; r < 4; ++r)
        Pf[w][(quad * 4 + r) * PH + nf * 16 + l16] = (_Float16)acc[nf][r];
#pragma unroll
    for (int kb = 0; kb < 2; ++kb) {
      half8 pa = *(const half8*)&Pf[w][l16 * PH + kb * 32 + quad * 8];
#pragma unroll
      for (int df = 0; df < 4; ++df) {
        half8 vf = *(const half8*)&VT[g][(df * 16 + l16) * KSTR + kb * 32 + quad * 8];
        oc[df] = __builtin_amdgcn_mfma_f32_16x16x32_f16(pa, vf, oc[df], 0, 0, 0);
      }
    }
  }
  __syncthreads();
  float lred[4];
#pragma unroll
  for (int r = 0; r < 4; ++r) {
    float s = l_r[r];
    s += __shfl_xor(s, 1); s += __shfl_xor(s, 2);
    s += __shfl_xor(s, 4); s += __shfl_xor(s, 8);
    lred[r] = s;
  }
  if (g == 1) {
#pragma unroll
    for (int df = 0; df < 4; ++df)
#pragma unroll
      for (int r = 0; r < 4; ++r)
        comb[qw][quad * 4 + r][df * 16 + l16] = oc[df][r];
    if (l16 == 0) {
#pragma unroll
      for (int r = 0; r < 4; ++r) combl[qw][quad * 4 + r] = lred[r];
    }
  }
  __syncthreads();
  if (g == 0) {
    float inv_l[4];
#pragma unroll
    for (int r = 0; r < 4; ++r)
      inv_l[r] = 1.f / (lred[r] + combl[qw][quad * 4 + r]);
#pragma unroll
    for (int df = 0; df < 4; ++df)
#pragma unroll
      for (int r = 0; r < 4; ++r) {
        int qrow = q0 + qw * 16 + quad * 4 + r;
        float v = oc[df][r] + comb[qw][quad * 4 + r][df * 16 + l16];
        out[(((size_t)(b * L_ + qrow)) * H_ + h) * D_ + df * 16 + l16] = v * inv_l[r];
      }
  }
}

extern "C" void kernel_launch(void* const* d_in, const int* in_sizes, int n_in,
                              void* d_out, int out_size, void* d_ws, size_t ws_size,
                              hipStream_t stream) {
  const float* qs = (const float*)d_in[0];
  const float* ks = (const float*)d_in[1];
  const float* vs = (const float*)d_in[2];
  const float* qs_s = (const float*)d_in[3];
  const float* ks_s = (const float*)d_in[4];
  const float* ap = (const float*)d_in[5];
  const float* bp = (const float*)d_in[6];
  const float* cp = (const float*)d_in[7];
  float* out = (float*)d_out;

  if (ws_size >= (size_t)WS_NEED) {
    _Float16* wsh = (_Float16*)d_ws;
    tisa_preproc<<<dim3(512), dim3(256), 0, stream>>>(qs, ks, vs, ks_s, wsh);
    tisa_attn_main<<<dim3(512), dim3(1024), 0, stream>>>(qs_s, ap, bp, cp, wsh, out);
  } else {
    tisa_attn_fallback<<<dim3(512), dim3(512), 0, stream>>>(qs, ks, vs, qs_s, ks_s, ap, bp, cp, out);
  }
}

// Round 7
// 134.799 us; speedup vs baseline: 1.8825x; 1.1187x over previous
//
#include <hip/hip_runtime.h>
#include <cmath>

typedef _Float16 half8 __attribute__((ext_vector_type(8)));
typedef _Float16 half2v __attribute__((ext_vector_type(2)));
typedef float f32x4 __attribute__((ext_vector_type(4)));
typedef float f32x2 __attribute__((ext_vector_type(2)));

#define B_ 2
#define L_ 2048
#define H_ 8
#define D_ 64
#define S_ 2
#define F_ 5
#define LUTN 2048
#define LSCALE 1448.1547f          // LUTN / sqrt(2)
#define LOG2E 1.44269504f
#define QSC (0.125f * LOG2E)       // folded into Q at preprocess

// ws layout: Q tiles (64x64 f16, swizzled), K tiles (32x64 f16, swizzled),
// VT tiles (superrow-swizzled f16), then pre-scaled ks_s coords (f32).
#define QOFF 0            // halfs
#define KOFF 2097152      // halfs
#define VOFF 4194304      // halfs
#define SOFFH 6291456     // halfs -> (float*)(wsh + SOFFH)
#define WS_NEED 12615680  // bytes

// main-kernel LDS arena offsets (bytes)
#define OFF_K 0            // 4 groups x 4096 (Q tile overlays groups 0-1 pre-loop)
#define OFF_V 16384        // 4 groups x 4096
#define OFF_P 32768        // 16 waves x 1280  (16 rows x 40 halfs)
#define OFF_LUT 53248      // 2049 x 4 (+pad) = 8208
#define OFF_KSS 61456      // 4 groups x 256 B (32 keys x f32x2) -> ends at 62480
#define ARENA_SZ 62480
#define SLOTF (16 * 68 + 16)   // combine slot: O[16][68] f32 + l[16]

#define GLOBAL_LOAD_LDS16(g, l)                                                  \
  __builtin_amdgcn_global_load_lds((const __attribute__((address_space(1))) void*)(g), \
                                   (__attribute__((address_space(3))) void*)(l), 16, 0, 0)

// raw v_sqrt_f32 (1 ULP) — sqrtf() without fast-math emits the IEEE fixup
// sequence (~10 VALU ops); result only feeds a 2048-bin LUT quantizer.
#define FAST_SQRT(x) __builtin_amdgcn_sqrtf(x)

// ---------------- preprocessing: f32 -> f16 swizzled tiles in ws ----------------
// grid 512 = (b,h,u), u in [0,32): Q-tile u (64 rows), K/V tiles 2u, 2u+1 (32 rows).
__global__ __launch_bounds__(256, 4)
void tisa_preproc(const float* __restrict__ qs, const float* __restrict__ ks,
                  const float* __restrict__ vs, const float* __restrict__ ks_s,
                  _Float16* __restrict__ wsh) {
  __shared__ _Float16 Vl[64 * 72];
  const int t = threadIdx.x;
  const int u = blockIdx.x & 31;
  const int bh = blockIdx.x >> 5;
  const size_t base = ((size_t)(bh >> 3) * L_ + (size_t)u * 64) * (H_ * D_) + (size_t)(bh & 7) * D_;

  // ---- Q: 512 chunks of 8 f32 -> 8 f16, swizzled chunk c^(row&7), scaled by QSC ----
#pragma unroll
  for (int jj = 0; jj < 2; ++jj) {
    int id = t * 2 + jj;              // 0..511
    int row = id >> 3, c = id & 7;
    const float* src = qs + base + (size_t)row * 512 + c * 8;
    f32x4 x0 = ((const f32x4*)src)[0], x1 = ((const f32x4*)src)[1];
    half8 hh;
#pragma unroll
    for (int k = 0; k < 4; ++k) { hh[k] = (_Float16)(x0[k] * QSC); hh[k + 4] = (_Float16)(x1[k] * QSC); }
    *(half8*)&wsh[QOFF + ((size_t)bh * 32 + u) * 4096 + row * 64 + (c ^ (row & 7)) * 8] = hh;
  }
  // ---- K: two 32-row tiles, same chunk swizzle ----
#pragma unroll
  for (int jj = 0; jj < 2; ++jj) {
    int id = t * 2 + jj;
    int tile = id >> 8, row = (id >> 3) & 31, c = id & 7;
    const float* src = ks + base + (size_t)(tile * 32 + row) * 512 + c * 8;
    f32x4 x0 = ((const f32x4*)src)[0], x1 = ((const f32x4*)src)[1];
    half8 hh;
#pragma unroll
    for (int k = 0; k < 4; ++k) { hh[k] = (_Float16)x0[k]; hh[k + 4] = (_Float16)x1[k]; }
    *(half8*)&wsh[KOFF + ((size_t)bh * 64 + u * 2 + tile) * 2048 + row * 64 + (c ^ (row & 7)) * 8] = hh;
  }
  // ---- scaled ks_s coords (h==0 blocks only; 64 keys = 128 floats) ----
  if ((bh & 7) == 0 && t < 32) {
    const int b = bh >> 3;
    const float* src = ks_s + ((size_t)b * L_ + u * 64) * 2 + t * 4;
    float* dst = (float*)(wsh + SOFFH) + ((size_t)b * L_ + u * 64) * 2 + t * 4;
    f32x4 x = *(const f32x4*)src;
    x *= LSCALE;
    *(f32x4*)dst = x;
  }
  // ---- V: stage f16 in LDS, then transposed superrow-swizzled tiles ----
  {
    int key = t >> 2, d0 = (t & 3) * 16;
    const float* src = vs + base + (size_t)key * 512 + d0;
    f32x4 a0 = ((const f32x4*)src)[0], a1 = ((const f32x4*)src)[1];
    f32x4 a2 = ((const f32x4*)src)[2], a3 = ((const f32x4*)src)[3];
    half8 h0, h1;
#pragma unroll
    for (int k = 0; k < 4; ++k) {
      h0[k] = (_Float16)a0[k]; h0[k + 4] = (_Float16)a1[k];
      h1[k] = (_Float16)a2[k]; h1[k + 4] = (_Float16)a3[k];
    }
    *(half8*)&Vl[key * 72 + d0] = h0;
    *(half8*)&Vl[key * 72 + d0 + 8] = h1;
  }
  __syncthreads();
  // superrow s holds d=2s,2s+1; slot c' = (d&1)*4 + (k>>3); stored at c'^(s&7)
#pragma unroll
  for (int jj = 0; jj < 2; ++jj) {
    int id = t * 2 + jj;
    int tile = id >> 8, s = (id >> 3) & 31, cp = id & 7;
    int d = 2 * s + (cp >> 2), kb = (cp & 3) * 8;
    half8 hh;
#pragma unroll
    for (int j = 0; j < 8; ++j) hh[j] = Vl[(tile * 32 + kb + j) * 72 + d];
    *(half8*)&wsh[VOFF + ((size_t)bh * 64 + u * 2 + tile) * 2048 + s * 64 + (cp ^ (s & 7)) * 8] = hh;
  }
}

// ---------------- main kernel: 1024 thr = 4 q-slices x 4 K-quarters ----------------
__global__ __launch_bounds__(1024, 8)
void tisa_attn_main(const float* __restrict__ qs_s, const float* __restrict__ ap,
                    const float* __restrict__ bp, const float* __restrict__ cp,
                    const _Float16* __restrict__ wsh, float* __restrict__ out) {
  __shared__ __align__(16) char arena[ARENA_SZ];
  float* LUT = (float*)(arena + OFF_LUT);

  const int t = threadIdx.x;
  const int lane = t & 63;
  const int w = t >> 6;       // 0..15
  const int g = w >> 2;       // K-quarter 0..3
  const int qw = w & 3;       // q-slice 0..3
  const int t2 = t & 255;     // index within group
  const int quad = lane >> 4;
  const int l16 = lane & 15;

  const int qt = blockIdx.x & 31;
  const int bh = blockIdx.x >> 5;
  const int h = bh & 7;
  const int b = bh >> 3;
  const int q0 = qt * 64;

  // ---- LUT (nearest-neighbor, midpoint-sampled): ((bias-8)*log2e) at d=(i+0.5)/LSCALE ----
  {
    float af[F_], nb[F_], cf[F_];
#pragma unroll
    for (int f = 0; f < F_; ++f) {
      af[f] = ap[h * F_ + f];
      nb[f] = -fabsf(bp[h * F_ + f]);
      cf[f] = cp[h * F_ + f];
    }
    for (int i = t; i <= LUTN; i += 1024) {
      float d = ((float)i + 0.5f) * (1.0f / LSCALE);
      float s = 0.f;
#pragma unroll
      for (int f = 0; f < F_; ++f) {
        float e = d - cf[f];
        s += af[f] * __expf(nb[f] * (e * e));
      }
      LUT[i] = (s - 8.0f) * LOG2E;
    }
  }

  // q coords (pre-scaled by LSCALE) for rows qw*16 + quad*4 + r
  float qx[4], qy[4];
#pragma unroll
  for (int r = 0; r < 4; ++r) {
    int qrow = q0 + qw * 16 + quad * 4 + r;
    qx[r] = qs_s[((size_t)b * L_ + qrow) * 2 + 0] * LSCALE;
    qy[r] = qs_s[((size_t)b * L_ + qrow) * 2 + 1] * LSCALE;
  }

  const _Float16* Qt = wsh + QOFF + ((size_t)bh * 32 + qt) * 4096;
  const _Float16* Kbh = wsh + KOFF + (size_t)bh * 64 * 2048;
  const _Float16* Vbh = wsh + VOFF + (size_t)bh * 64 * 2048;
  const float* wsS = (const float*)(wsh + SOFFH);

  // ---- Q tile (8 KB) -> arena[OFF_K..], waves 0..7 ----
  if (w < 8)
    GLOBAL_LOAD_LDS16(Qt + w * 512 + lane * 8, arena + OFF_K + w * 1024);
  __syncthreads();  // Q staged (+LUT built)

  half8 qA[2];
#pragma unroll
  for (int kb = 0; kb < 2; ++kb)
    qA[kb] = *(const half8*)(arena + OFF_K + (qw * 16 + l16) * 128 +
                             ((kb * 4 + quad) ^ (l16 & 7)) * 16);

  f32x4 oc[4];
#pragma unroll
  for (int df = 0; df < 4; ++df) oc[df] = (f32x4){0.f, 0.f, 0.f, 0.f};
  f32x4 lsacc = (f32x4){0.f, 0.f, 0.f, 0.f};
  half8 onesv;
#pragma unroll
  for (int j = 0; j < 8; ++j) onesv[j] = (_Float16)1.0f;

  const _Float16* ksrc = Kbh + (size_t)(g * 16) * 2048 + t2 * 8;
  const _Float16* vsrc = Vbh + (size_t)(g * 16) * 2048 + t2 * 8;
  const f32x2* ssrc = (const f32x2*)(wsS + ((size_t)b * L_ + g * 512) * 2);  // pre-scaled coords
  char* kdst = arena + OFF_K + g * 4096 + qw * 1024;   // wave-uniform
  char* vdst = arena + OFF_V + g * 4096 + qw * 1024;
  f32x2* kssG = (f32x2*)(arena + OFF_KSS + g * 256);
  _Float16* Pw = (_Float16*)(arena + OFF_P + w * 1280 + quad * 320 + l16 * 2);

  for (int it = 0; it < 16; ++it) {
    __syncthreads();  // prev iter's frag reads done (iter 0: qA reads done)
    GLOBAL_LOAD_LDS16(ksrc, kdst);
    GLOBAL_LOAD_LDS16(vsrc, vdst);
    ksrc += 2048; vsrc += 2048;
    if (t2 < 32) kssG[t2] = ssrc[t2];   // plain copy (coords pre-scaled in ws)
    ssrc += 32;
    __syncthreads();  // tiles + coords visible (barrier drains vmcnt/lgkmcnt)

    // ---- QK^T: 4 MFMA ----
    f32x4 acc[2];
#pragma unroll
    for (int nf = 0; nf < 2; ++nf) {
      f32x4 a = (f32x4){0.f, 0.f, 0.f, 0.f};
#pragma unroll
      for (int kb = 0; kb < 2; ++kb) {
        half8 kf = *(const half8*)(arena + OFF_K + g * 4096 + (nf * 16 + l16) * 128 +
                                   ((kb * 4 + quad) ^ (l16 & 7)) * 16);
        a = __builtin_amdgcn_mfma_f32_16x16x32_f16(qA[kb], kf, a, 0, 0, 0);
      }
      acc[nf] = a;
    }

    // ---- scores: dist -> nearest-LUT -> exp2; P f16 scatter ----
#pragma unroll
    for (int nf = 0; nf < 2; ++nf) {
      f32x2 kc = kssG[nf * 16 + l16];
#pragma unroll
      for (int r = 0; r < 4; ++r) {
        float dx = qx[r] - kc.x, dy = qy[r] - kc.y;
        float tt = FAST_SQRT(fmaf(dx, dx, dy * dy));   // = dist * LSCALE
        int ii = (int)tt;
        float p = __builtin_amdgcn_exp2f(acc[nf][r] + LUT[ii]);
        acc[nf][r] = p;
        Pw[r * 40 + nf * 16] = (_Float16)p;   // P[qrow=quad*4+r][key=nf*16+l16]
      }
    }

    // ---- PV + row-sum via ones-MFMA; same-wave DS ordering, no barrier ----
    half8 pa = *(const half8*)(arena + OFF_P + w * 1280 + l16 * 80 + quad * 16);
    lsacc = __builtin_amdgcn_mfma_f32_16x16x32_f16(pa, onesv, lsacc, 0, 0, 0);
#pragma unroll
    for (int df = 0; df < 4; ++df) {
      half8 vf = *(const half8*)(arena + OFF_V + g * 4096 + (l16 >> 1) * 128 + df * 1024 +
                                 ((((l16 & 1) * 4 + quad) ^ ((l16 >> 1) & 7)) * 16));
      oc[df] = __builtin_amdgcn_mfma_f32_16x16x32_f16(pa, vf, oc[df], 0, 0, 0);
    }
  }

  // ---- combine 4 K-quarters via LDS tree (row sums already reduced by ones-MFMA) ----
  float lred[4];
#pragma unroll
  for (int r = 0; r < 4; ++r) lred[r] = lsacc[r];
  __syncthreads();  // all loop LDS reads done; arena reusable
  float* slots = (float*)arena;
  if (g >= 2) {
    float* sl = slots + ((g - 2) * 4 + qw) * SLOTF;
#pragma unroll
    for (int df = 0; df < 4; ++df)
#pragma unroll
      for (int r = 0; r < 4; ++r)
        sl[(quad * 4 + r) * 68 + df * 16 + l16] = oc[df][r];
    if (l16 == 0) {
#pragma unroll
      for (int r = 0; r < 4; ++r) sl[16 * 68 + quad * 4 + r] = lred[r];
    }
  }
  __syncthreads();
  if (g < 2) {
    float* sl = slots + (g * 4 + qw) * SLOTF;   // g0<-slot(g2), g1<-slot(g3)
#pragma unroll
    for (int df = 0; df < 4; ++df)
#pragma unroll
      for (int r = 0; r < 4; ++r)
        oc[df][r] += sl[(quad * 4 + r) * 68 + df * 16 + l16];
#pragma unroll
    for (int r = 0; r < 4; ++r) lred[r] += sl[16 * 68 + quad * 4 + r];
  }
  if (g == 1) {  // write combined back into same slot (same-wave, in-order)
    float* sl = slots + (4 + qw) * SLOTF;
#pragma unroll
    for (int df = 0; df < 4; ++df)
#pragma unroll
      for (int r = 0; r < 4; ++r)
        sl[(quad * 4 + r) * 68 + df * 16 + l16] = oc[df][r];
    if (l16 == 0) {
#pragma unroll
      for (int r = 0; r < 4; ++r) sl[16 * 68 + quad * 4 + r] = lred[r];
    }
  }
  __syncthreads();
  if (g == 0) {
    float* sl = slots + (4 + qw) * SLOTF;
    float inv_l[4];
#pragma unroll
    for (int r = 0; r < 4; ++r)
      inv_l[r] = 1.f / (lred[r] + sl[16 * 68 + quad * 4 + r]);
#pragma unroll
    for (int df = 0; df < 4; ++df)
#pragma unroll
      for (int r = 0; r < 4; ++r) {
        int qrow = q0 + qw * 16 + quad * 4 + r;
        float v = oc[df][r] + sl[(quad * 4 + r) * 68 + df * 16 + l16];
        out[((size_t)(b * L_ + qrow)) * (H_ * D_) + h * D_ + df * 16 + l16] = v * inv_l[r];
      }
  }
}

// ---------------- fallback (R3 kernel) if ws too small ----------------
#define KSTR 72
#define PH 72
#define FLUTN 512
#define FLSCALE 362.03867f
__global__ __launch_bounds__(512, 4)
void tisa_attn_fallback(const float* __restrict__ qs, const float* __restrict__ ks,
                        const float* __restrict__ vs, const float* __restrict__ qs_s,
                        const float* __restrict__ ks_s, const float* __restrict__ ap,
                        const float* __restrict__ bp, const float* __restrict__ cp,
                        float* __restrict__ out) {
  __shared__ _Float16 Ks[2][64 * KSTR];
  __shared__ _Float16 VT[2][D_ * KSTR];
  __shared__ _Float16 Pf[8][16 * PH];
  __shared__ float kss2[2][64 * 2];
  __shared__ f32x2 LUT2s[FLUTN + 1];
  __shared__ float comb[4][16][64];
  __shared__ float combl[4][16];

  const int t = threadIdx.x;
  const int lane = t & 63;
  const int w = t >> 6;
  const int g = w >> 2;
  const int qw = w & 3;
  const int t2 = t & 255;
  const int quad = lane >> 4;
  const int l16 = lane & 15;
  const int qt = blockIdx.x & 31;
  const int bh = blockIdx.x >> 5;
  const int h = bh & 7;
  const int b = bh >> 3;
  const int q0 = qt * 64;

  float af[F_], nb[F_], cf[F_];
#pragma unroll
  for (int f = 0; f < F_; ++f) {
    af[f] = ap[h * F_ + f];
    nb[f] = -fabsf(bp[h * F_ + f]);
    cf[f] = cp[h * F_ + f];
  }
  for (int i = t; i <= FLUTN; i += 512) {
    float d0 = (float)i * (1.0f / FLSCALE), d1 = (float)(i + 1) * (1.0f / FLSCALE);
    float s0 = 0.f, s1 = 0.f;
#pragma unroll
    for (int f = 0; f < F_; ++f) {
      float e0 = d0 - cf[f], e1 = d1 - cf[f];
      s0 += af[f] * __expf(nb[f] * (e0 * e0));
      s1 += af[f] * __expf(nb[f] * (e1 * e1));
    }
    LUT2s[i] = (f32x2){s0 - 8.0f, s1 - 8.0f};
  }
  float qx[4], qy[4];
#pragma unroll
  for (int r = 0; r < 4; ++r) {
    int qrow = q0 + qw * 16 + quad * 4 + r;
    qx[r] = qs_s[(b * L_ + qrow) * S_ + 0];
    qy[r] = qs_s[(b * L_ + qrow) * S_ + 1];
  }
  if (t < 256) {
    const int row = t >> 2, dc = (t & 3) * 16;
    const float* src = qs + (((size_t)(b * L_ + q0 + row)) * H_ + h) * D_ + dc;
    const f32x4* s4 = (const f32x4*)src;
    f32x4 v0 = s4[0], v1 = s4[1], v2 = s4[2], v3 = s4[3];
    half8 w0, w1;
#pragma unroll
    for (int u = 0; u < 4; ++u) {
      w0[u] = (_Float16)(v0[u] * 0.125f); w0[u + 4] = (_Float16)(v1[u] * 0.125f);
      w1[u] = (_Float16)(v2[u] * 0.125f); w1[u + 4] = (_Float16)(v3[u] * 0.125f);
    }
    *(half8*)&Ks[0][row * KSTR + dc] = w0;
    *(half8*)&Ks[0][row * KSTR + dc + 8] = w1;
  }
  __syncthreads();
  half8 qA[2];
#pragma unroll
  for (int kb = 0; kb < 2; ++kb)
    qA[kb] = *(const half8*)&Ks[0][(qw * 16 + l16) * KSTR + kb * 32 + quad * 8];
  f32x4 oc[4];
#pragma unroll
  for (int df = 0; df < 4; ++df) oc[df] = (f32x4){0.f, 0.f, 0.f, 0.f};
  float l_r[4] = {0.f, 0.f, 0.f, 0.f};

  for (int it = 0; it < 16; ++it) {
    const int k0 = (g * 16 + it) * 64;
    __syncthreads();
    {
      const int row = t2 >> 2, dc = (t2 & 3) * 16;
      const float* src = ks + (((size_t)(b * L_ + k0 + row)) * H_ + h) * D_ + dc;
      const f32x4* s4 = (const f32x4*)src;
      f32x4 v0 = s4[0], v1 = s4[1], v2 = s4[2], v3 = s4[3];
      half8 w0, w1;
#pragma unroll
      for (int u = 0; u < 4; ++u) {
        w0[u] = (_Float16)v0[u]; w0[u + 4] = (_Float16)v1[u];
        w1[u] = (_Float16)v2[u]; w1[u + 4] = (_Float16)v3[u];
      }
      *(half8*)&Ks[g][row * KSTR + dc] = w0;
      *(half8*)&Ks[g][row * KSTR + dc + 8] = w1;
    }
    {
      const int kk = (t2 & 31) * 2, dg = (t2 >> 5) * 8;
      const float* s0 = vs + (((size_t)(b * L_ + k0 + kk)) * H_ + h) * D_ + dg;
      const float* s1 = s0 + H_ * D_;
      f32x4 a0 = ((const f32x4*)s0)[0], a1 = ((const f32x4*)s0)[1];
      f32x4 b0 = ((const f32x4*)s1)[0], b1 = ((const f32x4*)s1)[1];
#pragma unroll
      for (int u = 0; u < 4; ++u) {
        half2v p0 = {(_Float16)a0[u], (_Float16)b0[u]};
        *(half2v*)&VT[g][(dg + u) * KSTR + kk] = p0;
        half2v p1 = {(_Float16)a1[u], (_Float16)b1[u]};
        *(half2v*)&VT[g][(dg + 4 + u) * KSTR + kk] = p1;
      }
    }
    if (t2 < 128) kss2[g][t2] = ks_s[((size_t)(b * L_) + k0 + (t2 >> 1)) * S_ + (t2 & 1)];
    __syncthreads();
    f32x4 acc[4];
#pragma unroll
    for (int nf = 0; nf < 4; ++nf) {
      f32x4 a = (f32x4){0.f, 0.f, 0.f, 0.f};
#pragma unroll
      for (int kb = 0; kb < 2; ++kb) {
        half8 kf = *(const half8*)&Ks[g][(nf * 16 + l16) * KSTR + kb * 32 + quad * 8];
        a = __builtin_amdgcn_mfma_f32_16x16x32_f16(qA[kb], kf, a, 0, 0, 0);
      }
      acc[nf] = a;
    }
#pragma unroll
    for (int nf = 0; nf < 4; ++nf) {
      float kx = kss2[g][(nf * 16 + l16) * 2 + 0];
      float ky = kss2[g][(nf * 16 + l16) * 2 + 1];
#pragma unroll
      for (int r = 0; r < 4; ++r) {
        float dx = qx[r] - kx, dy = qy[r] - ky;
        float dist = FAST_SQRT(fmaf(dx, dx, dy * dy));
        float tt = dist * FLSCALE;
        int ii = (int)tt;
        float fr = tt - (float)ii;
        f32x2 lh = LUT2s[ii];
        float p = __expf(acc[nf][r] + fmaf(fr, lh.y - lh.x, lh.x));
        acc[nf][r] = p;
      }
    }
#pragma unroll
    for (int r = 0; r < 4; ++r)
      l_r[r] += (acc[0][r] + acc[1][r]) + (acc[2][r] + acc[3][r]);
#pragma unroll
    for (int nf = 0; nf < 4; ++nf)
#pragma unroll
      for (int r = 0; r < 4; ++r)
        Pf[w][(quad * 4 + r) * PH + nf * 16 + l16] = (_Float16)acc[nf][r];
#pragma unroll
    for (int kb = 0; kb < 2; ++kb) {
      half8 pa = *(const half8*)&Pf[w][l16 * PH + kb * 32 + quad * 8];
#pragma unroll
      for (int df = 0; df < 4; ++df) {
        half8 vf = *(const half8*)&VT[g][(df * 16 + l16) * KSTR + kb * 32 + quad * 8];
        oc[df] = __builtin_amdgcn_mfma_f32_16x16x32_f16(pa, vf, oc[df], 0, 0, 0);
      }
    }
  }
  __syncthreads();
  float lred[4];
#pragma unroll
  for (int r = 0; r < 4; ++r) {
    float s = l_r[r];
    s += __shfl_xor(s, 1); s += __shfl_xor(s, 2);
    s += __shfl_xor(s, 4); s += __shfl_xor(s, 8);
    lred[r] = s;
  }
  if (g == 1) {
#pragma unroll
    for (int df = 0; df < 4; ++df)
#pragma unroll
      for (int r = 0; r < 4; ++r)
        comb[qw][quad * 4 + r][df * 16 + l16] = oc[df][r];
    if (l16 == 0) {
#pragma unroll
      for (int r = 0; r < 4; ++r) combl[qw][quad * 4 + r] = lred[r];
    }
  }
  __syncthreads();
  if (g == 0) {
    float inv_l[4];
#pragma unroll
    for (int r = 0; r < 4; ++r)
      inv_l[r] = 1.f / (lred[r] + combl[qw][quad * 4 + r]);
#pragma unroll
    for (int df = 0; df < 4; ++df)
#pragma unroll
      for (int r = 0; r < 4; ++r) {
        int qrow = q0 + qw * 16 + quad * 4 + r;
        float v = oc[df][r] + comb[qw][quad * 4 + r][df * 16 + l16];
        out[(((size_t)(b * L_ + qrow)) * H_ + h) * D_ + df * 16 + l16] = v * inv_l[r];
      }
  }
}

extern "C" void kernel_launch(void* const* d_in, const int* in_sizes, int n_in,
                              void* d_out, int out_size, void* d_ws, size_t ws_size,
                              hipStream_t stream) {
  const float* qs = (const float*)d_in[0];
  const float* ks = (const float*)d_in[1];
  const float* vs = (const float*)d_in[2];
  const float* qs_s = (const float*)d_in[3];
  const float* ks_s = (const float*)d_in[4];
  const float* ap = (const float*)d_in[5];
  const float* bp = (const float*)d_in[6];
  const float* cp = (const float*)d_in[7];
  float* out = (float*)d_out;

  if (ws_size >= (size_t)WS_NEED) {
    _Float16* wsh = (_Float16*)d_ws;
    tisa_preproc<<<dim3(512), dim3(256), 0, stream>>>(qs, ks, vs, ks_s, wsh);
    tisa_attn_main<<<dim3(512), dim3(1024), 0, stream>>>(qs_s, ap, bp, cp, wsh, out);
  } else {
    tisa_attn_fallback<<<dim3(512), dim3(512), 0, stream>>>(qs, ks, vs, qs_s, ks_s, ap, bp, cp, out);
  }
}